// Round 7
// baseline (1817.081 us; speedup 1.0000x reference)
//
#include <hip/hip_runtime.h>

// ============================================================================
// TemporalPointNet (PointNet++ style) forward on MI355X.
// B=2, T=4 -> BT=8 "batches", N=4096 points, 4 coords (xyz + t).
// SA1: npoint=512, r=0.2, K=32, C_in=4,  MLP 64,64,128
// SA2: npoint=128, r=0.4, K=64, C_in=131, MLP 128,128,256
// SA3: group_all,          K=128, C_in=259, MLP 256,512,1024
//
// R18: back to R13 structure (measured 826us; full-size grid per gemm) after
// R17 proved coop fusion LOSES (mlp_coop 643us alone: grid-wide sync forces
// the whole MLP to co-resident grid ~256 blocks; latency-bound gemms scaled
// ~4x worse; occupancy 12%). Boundary removal now done WITHOUT shrinking
// grids:
//  (a) finalize_bn fused into its producing gemm as a last-block-done tail
//      (threadfence + per-layer atomic ticket; last block reduces part ->
//      scales/shifts). Removes 9 dispatches; gemm grids unchanged.
//      Finalize sum = 4-way interleaved serial per channel (deterministic,
//      double; ~1e-13 reorder vs old tree — threshold 0.123, we're at 0.03).
//  (b) SA1 bn_relu_max + SA2 query_ball fused into one dispatch (independent;
//      both inputs ready after L1_2). -1 dispatch.
//  (c) prep_w piggyback in fps_block; fps_wave piggyback in qb_group1 (both
//      proven). FPS critical chains byte-identical to R11/R13 (286us best).
// Dispatches 27 -> 17. GEMM math bit-identical to R13 (split-bf16 triple
// MFMA, same stats layout/order at the part level).
// ============================================================================

typedef short s16x8 __attribute__((ext_vector_type(8)));
typedef float f32x4 __attribute__((ext_vector_type(4)));

__device__ __forceinline__ unsigned short f2bf_rne(float f) {
    unsigned u = __float_as_uint(f);
    u += 0x7FFFu + ((u >> 16) & 1u);
    return (unsigned short)(u >> 16);
}
// split f32 -> (hi, lo) bf16 pair: hi = rne(v), lo = rne(v - hi)
__device__ __forceinline__ void f2bf_split(float v, unsigned short& hi,
                                           unsigned short& lo) {
    unsigned u = __float_as_uint(v);
    unsigned r = u + 0x7FFFu + ((u >> 16) & 1u);
    hi = (unsigned short)(r >> 16);
    float vh = __uint_as_float(r & 0xFFFF0000u);
    lo = f2bf_rne(v - vh);
}

__device__ __forceinline__ unsigned long long umax64(unsigned long long a,
                                                     unsigned long long b) {
    return a > b ? a : b;
}

// Wave64 max-reduce via DPP: 1 DPP + 1 max per step (R9 measured-best;
// R10/R12 variants regressed — do not touch).
__device__ __forceinline__ unsigned wred_umax63(unsigned v) {
    unsigned t;
    t = (unsigned)__builtin_amdgcn_update_dpp(0, (int)v, 0x111, 0xf, 0xf, true); if (t > v) v = t;
    t = (unsigned)__builtin_amdgcn_update_dpp(0, (int)v, 0x112, 0xf, 0xf, true); if (t > v) v = t;
    t = (unsigned)__builtin_amdgcn_update_dpp(0, (int)v, 0x114, 0xf, 0xf, true); if (t > v) v = t;
    t = (unsigned)__builtin_amdgcn_update_dpp(0, (int)v, 0x118, 0xf, 0xf, true); if (t > v) v = t;
    t = (unsigned)__builtin_amdgcn_update_dpp(0, (int)v, 0x142, 0xa, 0xf, true); if (t > v) v = t;
    t = (unsigned)__builtin_amdgcn_update_dpp(0, (int)v, 0x143, 0xc, 0xf, true); if (t > v) v = t;
    return v;
}

// Wave argmax of (dist, min-index). Exact first-occurrence argmax.
__device__ __forceinline__ void wave_argmax(unsigned dbits, unsigned nInv,
                                            unsigned& vmax, unsigned& iInv) {
    unsigned m = wred_umax63(dbits);
    vmax = (unsigned)__builtin_amdgcn_readlane((int)m, 63);
    unsigned cand = (dbits == vmax) ? nInv : 0u;
    unsigned im = wred_umax63(cand);
    iInv = (unsigned)__builtin_amdgcn_readlane((int)im, 63);
}

// ---------------- all-layer weight pre-split (device body) ----------------
struct PWArgs {
    const float* w[9];
    unsigned off[9];
    int O[9], C[9], CP[9];
};
__device__ __forceinline__ void prep_w_dev(const PWArgs& a,
                                           unsigned short* __restrict__ wh,
                                           unsigned short* __restrict__ wl,
                                           int i) {
    int l = 0;
#pragma unroll
    for (int k = 1; k < 9; ++k) if (i >= (int)a.off[k]) l = k;
    int li = i - (int)a.off[l];
    int CP = a.CP[l];
    int o = li / CP;
    int c = li - o * CP;
    float v = (c < a.C[l]) ? a.w[l][(size_t)o * a.C[l] + c] : 0.f;
    unsigned short h, lo;
    f2bf_split(v, h, lo);
    wh[i] = h; wl[i] = lo;
}

// ---------------- FPS (multi-wave): one block (NT thr) per batch ------------
// R7/R9 structure (measured best 286us). Blocks >= nFps run the weight
// pre-split (fully hidden in the FPS shadow).
template<int NT, int ITEMS, int STRIDE>
__global__ __launch_bounds__(NT) void fps_block(
    const float* __restrict__ pts, int npoint,
    int* __restrict__ outIdx, float* __restrict__ outXyz,
    int nFps, PWArgs pw, unsigned short* __restrict__ wh,
    unsigned short* __restrict__ wl, int wtotal)
{
    constexpr int N = NT * ITEMS;
    constexpr int NW = NT / 64;
    __shared__ float4 scoord[N];
    __shared__ unsigned long long wkey[2][NW];

    if (blockIdx.x >= nFps) {   // piggyback: weight split on idle CUs
        int i = (blockIdx.x - nFps) * NT + threadIdx.x;
        if (i < wtotal) prep_w_dev(pw, wh, wl, i);
        return;
    }

    const int b = blockIdx.x;
    const int tid = threadIdx.x;
    const int wid = tid >> 6;
    const int lane = tid & 63;
    const float* P = pts + (size_t)b * N * STRIDE;

    float px[ITEMS], py[ITEMS], pz[ITEMS], dloc[ITEMS];
#pragma unroll
    for (int w = 0; w < ITEMS; ++w) {
        int n = tid + w * NT;
        float x, y, z;
        if (STRIDE == 4) {
            float4 v = *(const float4*)(P + (size_t)n * 4);
            x = v.x; y = v.y; z = v.z;
        } else {
            x = P[(size_t)n * STRIDE + 0];
            y = P[(size_t)n * STRIDE + 1];
            z = P[(size_t)n * STRIDE + 2];
        }
        px[w] = x; py[w] = y; pz[w] = z;
        scoord[n] = make_float4(x, y, z, 0.f);
        dloc[w] = 1e10f;
    }
    __syncthreads();
    float4 c0 = scoord[0];
    float cx = c0.x, cy = c0.y, cz = c0.z;
    int far = 0;

    for (int i = 0; i < npoint; ++i) {
        if (tid == 0) {
            outIdx[(size_t)b * npoint + i] = far;
            outXyz[((size_t)b * npoint + i) * 3 + 0] = cx;
            outXyz[((size_t)b * npoint + i) * 3 + 1] = cy;
            outXyz[((size_t)b * npoint + i) * 3 + 2] = cz;
        }
        float bestV = -1.0f;
        int bestW = 0;
#pragma unroll
        for (int w = 0; w < ITEMS; ++w) {
            float dx = __fsub_rn(px[w], cx);
            float dy = __fsub_rn(py[w], cy);
            float dz = __fsub_rn(pz[w], cz);
            float d = __fadd_rn(__fadd_rn(__fmul_rn(dx, dx), __fmul_rn(dy, dy)),
                                __fmul_rn(dz, dz));
            float dd = fminf(dloc[w], d);
            dloc[w] = dd;
            if (dd > bestV) { bestV = dd; bestW = w; }  // strict > : lowest w kept
        }
        int bestN = tid + bestW * NT;   // n grows with w -> min n on tie
        unsigned vmax, iInv;
        wave_argmax(__float_as_uint(bestV), 0xFFFFFFFFu ^ (unsigned)bestN,
                    vmax, iInv);
        const int par = i & 1;
        if (lane == 0)
            wkey[par][wid] = ((unsigned long long)vmax << 32) | iInv;
        __syncthreads();   // single barrier per iteration (parity dbuf)
        unsigned long long kb = wkey[par][0];
#pragma unroll
        for (int w2 = 1; w2 < NW; ++w2) kb = umax64(kb, wkey[par][w2]);
        far = (int)(0xFFFFFFFFu ^ (unsigned)kb);
        float4 cc = scoord[far];   // broadcast, conflict-free
        cx = cc.x; cy = cc.y; cz = cc.z;
    }
}

// ---------------- FPS (single wave, device body, no barriers) ---------------
__device__ void fps_wave_dev(const float* __restrict__ pts, int npoint,
                             int* __restrict__ outIdx, float* __restrict__ outXyz,
                             int b, float4* scoord)
{
    constexpr int ITEMS = 8;
    constexpr int STRIDE = 3;
    constexpr int N = 64 * ITEMS;
    const int tid = threadIdx.x;   // 0..63
    const float* P = pts + (size_t)b * N * STRIDE;

    float px[ITEMS], py[ITEMS], pz[ITEMS], dloc[ITEMS];
#pragma unroll
    for (int w = 0; w < ITEMS; ++w) {
        int n = tid + w * 64;
        float x = P[(size_t)n * STRIDE + 0];
        float y = P[(size_t)n * STRIDE + 1];
        float z = P[(size_t)n * STRIDE + 2];
        px[w] = x; py[w] = y; pz[w] = z;
        scoord[n] = make_float4(x, y, z, 0.f);
        dloc[w] = 1e10f;
    }
    __threadfence_block();
    float4 c0 = scoord[0];
    float cx = c0.x, cy = c0.y, cz = c0.z;
    int far = 0;

    for (int i = 0; i < npoint; ++i) {
        if (tid == 0) {
            outIdx[(size_t)b * npoint + i] = far;
            outXyz[((size_t)b * npoint + i) * 3 + 0] = cx;
            outXyz[((size_t)b * npoint + i) * 3 + 1] = cy;
            outXyz[((size_t)b * npoint + i) * 3 + 2] = cz;
        }
        float bestV = -1.0f;
        int bestW = 0;
#pragma unroll
        for (int w = 0; w < ITEMS; ++w) {
            float dx = __fsub_rn(px[w], cx);
            float dy = __fsub_rn(py[w], cy);
            float dz = __fsub_rn(pz[w], cz);
            float d = __fadd_rn(__fadd_rn(__fmul_rn(dx, dx), __fmul_rn(dy, dy)),
                                __fmul_rn(dz, dz));
            float dd = fminf(dloc[w], d);
            dloc[w] = dd;
            if (dd > bestV) { bestV = dd; bestW = w; }
        }
        int bestN = tid + bestW * 64;
        unsigned vmax, iInv;
        wave_argmax(__float_as_uint(bestV), 0xFFFFFFFFu ^ (unsigned)bestN,
                    vmax, iInv);
        far = (int)(0xFFFFFFFFu ^ iInv);
        float4 cc = scoord[far];
        cx = cc.x; cy = cc.y; cz = cc.z;
    }
}

// ---------------- fused query_ball + group for SA1 (+fps_wave piggyback) ----
__global__ __launch_bounds__(256) void qb_group1(
    const float* __restrict__ xyz /*(8,4096,4)*/,
    const float* __restrict__ ctr /*(8*512,3)*/,
    float* __restrict__ out /*(8*512*32, 8)*/,
    int nQb, const float* __restrict__ fpsPts,
    int* __restrict__ fpsIdx, float* __restrict__ fpsXyz)
{
    __shared__ float4 scoord[512];
    if ((int)blockIdx.x >= nQb) {   // piggyback: single-wave FPS (SA2)
        if (threadIdx.x < 64)
            fps_wave_dev(fpsPts, 128, fpsIdx, fpsXyz,
                         (int)blockIdx.x - nQb, scoord);
        return;
    }
    int gw = (blockIdx.x * 256 + threadIdx.x) >> 6;
    int lane = threadIdx.x & 63;
    if (gw >= 4096) return;
    int b = gw >> 9;
    const float* P = xyz + (size_t)b * 4096 * 4;
    float cx = ctr[(size_t)gw * 3 + 0];
    float cy = ctr[(size_t)gw * 3 + 1];
    float cz = ctr[(size_t)gw * 3 + 2];
    float* out0 = out + (size_t)gw * 32 * 8;
    int cnt = 0;
    float f0x = 0.f, f0y = 0.f, f0z = 0.f, f0t = 0.f;
    bool haveFirst = false;
    for (int base = 0; base < 4096 && cnt < 32; base += 64) {
        int n = base + lane;
        float4 p = *(const float4*)(P + (size_t)n * 4);
        float ex = __fsub_rn(p.x, cx);
        float ey = __fsub_rn(p.y, cy);
        float ez = __fsub_rn(p.z, cz);
        float d = __fadd_rn(__fadd_rn(__fmul_rn(ex, ex), __fmul_rn(ey, ey)),
                            __fmul_rn(ez, ez));
        bool inb = !(d > 0.04f);
        unsigned long long mask = __ballot(inb);
        if (mask) {
            if (!haveFirst) {
                int fl = (int)__builtin_ctzll(mask);   // wave-uniform
                f0x = __shfl(ex, fl); f0y = __shfl(ey, fl);
                f0z = __shfl(ez, fl); f0t = __shfl(p.w, fl);
                haveFirst = true;
            }
            if (inb) {
                int pos = cnt + __builtin_popcountll(mask & ((1ull << lane) - 1ull));
                if (pos < 32) {
                    float* o = out0 + (size_t)pos * 8;
                    *(float4*)o = make_float4(ex, ey, ez, p.w);
                    *(float4*)(o + 4) = make_float4(0.f, 0.f, 0.f, 0.f);
                }
            }
            cnt += (int)__builtin_popcountll(mask);
        }
    }
    if (cnt > 32) cnt = 32;
    for (int p2 = cnt + lane; p2 < 32; p2 += 64) {
        float* o = out0 + (size_t)p2 * 8;
        *(float4*)o = make_float4(f0x, f0y, f0z, f0t);
        *(float4*)(o + 4) = make_float4(0.f, 0.f, 0.f, 0.f);
    }
}

// ---------------- query_ball body (SA2 geometry, device) ----------------
__device__ __forceinline__ void qb2_dev(
    const float* __restrict__ xyz, const float* __restrict__ centers,
    int* __restrict__ outIdx, int gw, int lane)
{
    const int N = 512, stride = 3, S = 128, nsample = 64;
    const float r2 = 0.16f;
    int b = gw / S;
    const float* P = xyz + (size_t)b * N * stride;
    float cx = centers[(size_t)gw * 3 + 0];
    float cy = centers[(size_t)gw * 3 + 1];
    float cz = centers[(size_t)gw * 3 + 2];
    int* out = outIdx + (size_t)gw * nsample;
    int cnt = 0;
    int firstIdx = 0;
    bool haveFirst = false;
    for (int base = 0; base < N && cnt < nsample; base += 64) {
        int n = base + lane;
        bool inb = false;
        if (n < N) {
            float dx = __fsub_rn(cx, P[(size_t)n * stride + 0]);
            float dy = __fsub_rn(cy, P[(size_t)n * stride + 1]);
            float dz = __fsub_rn(cz, P[(size_t)n * stride + 2]);
            float d = __fadd_rn(__fadd_rn(__fmul_rn(dx, dx), __fmul_rn(dy, dy)),
                                __fmul_rn(dz, dz));
            inb = !(d > r2);
        }
        unsigned long long mask = __ballot(inb);
        if (mask) {
            if (!haveFirst) { firstIdx = base + __builtin_ctzll(mask); haveFirst = true; }
            if (inb) {
                int pos = cnt + __builtin_popcountll(mask & ((1ull << lane) - 1ull));
                if (pos < nsample) out[pos] = n;
            }
            cnt += (int)__builtin_popcountll(mask);
        }
    }
    if (cnt > nsample) cnt = nsample;
    for (int p = cnt + lane; p < nsample; p += 64) out[p] = firstIdx;
}

// ---------------- grouping kernels (f32, padded rows) ----------------------
__global__ __launch_bounds__(256) void group2_kernel(
    const float* __restrict__ xyz, const float* __restrict__ feat,
    const int* __restrict__ qb, const float* __restrict__ ctr,
    float* __restrict__ out)
{
    int i = blockIdx.x * 256 + threadIdx.x;
    if (i >= 65536 * 136) return;
    int sk = i / 136;
    int c = i - sk * 136;
    int b = sk / (128 * 64);
    int bs = sk / 64;
    int idx = qb[sk];
    idx = (idx < 0) ? 0 : (idx > 511 ? 511 : idx);
    float v = 0.f;
    if (c < 3)        v = __fsub_rn(xyz[((size_t)b * 512 + idx) * 3 + c], ctr[(size_t)bs * 3 + c]);
    else if (c < 131) v = feat[((size_t)b * 512 + idx) * 128 + (c - 3)];
    out[i] = v;
}

__global__ __launch_bounds__(256) void group3_kernel(
    const float* __restrict__ ctr2, const float* __restrict__ feat2,
    float* __restrict__ out)
{
    int i = blockIdx.x * 256 + threadIdx.x;
    if (i >= 1024 * 264) return;
    int sk = i / 264;
    int c = i - sk * 264;
    float v = 0.f;
    if (c < 3)        v = ctr2[(size_t)sk * 3 + c];
    else if (c < 259) v = feat2[(size_t)sk * 256 + (c - 3)];
    out[i] = v;
}

// ---------------- fused GEMM: Y = act(X) * W^T + BN stats + finalize -------
// R13 body (bit-identical math). One 128x128 tile per block, grid
// (YB, OB). NEW: last-block-done tail (threadfence + per-layer atomic
// ticket) reduces part -> scales/shifts in the SAME dispatch, replacing the
// separate finalize_bn launch. Finalize: per-channel 4-way interleaved
// serial double sum (deterministic; ~1e-13 reorder vs old tree).
__global__ __launch_bounds__(256) void gemm_fused(
    const float* __restrict__ X,
    const float* __restrict__ scale, const float* __restrict__ shift,
    int applyAct,
    const unsigned short* __restrict__ Bh, const unsigned short* __restrict__ Bl,
    float* __restrict__ Y, double* __restrict__ part,
    int AC, int CPW, int O,
    const float* __restrict__ gvec, const float* __restrict__ bvec,
    float* __restrict__ scOut, float* __restrict__ shOut,
    double invM, unsigned* __restrict__ counter)
{
    constexpr int PITCH = 40;
    __shared__ __align__(16) unsigned short sAh[128 * PITCH];
    __shared__ __align__(16) unsigned short sAl[128 * PITCH];
    __shared__ __align__(16) unsigned short sBh[128 * PITCH];
    __shared__ __align__(16) unsigned short sBl[128 * PITCH];
    __shared__ float sred[2048];
    __shared__ int sLast;

    const int tid = threadIdx.x;
    const int lane = tid & 63;
    const int wid = tid >> 6;
    const int col15 = lane & 15;
    const int quad = lane >> 4;
    const int wm = (wid >> 1) * 64;
    const int wo = (wid & 1) * 64;
    const int m0 = blockIdx.x * 128;
    const int o0 = blockIdx.y * 128;
    const int YB = gridDim.x;
    const int lr = tid >> 2;
    const int lc = (tid & 3) * 8;

    f32x4 acc[4][4];
#pragma unroll
    for (int mt = 0; mt < 4; ++mt)
#pragma unroll
        for (int ot = 0; ot < 4; ++ot)
            acc[mt][ot] = {0.f, 0.f, 0.f, 0.f};

    for (int k0 = 0; k0 < CPW; k0 += 32) {
#pragma unroll
        for (int it = 0; it < 2; ++it) {
            int r = lr + it * 64;
            int c = k0 + lc;
            unsigned short h[8], l[8];
            if (c + 8 <= AC) {
                const float* xr = X + (size_t)(m0 + r) * AC + c;
                float4 v0 = *(const float4*)xr;
                float4 v1 = *(const float4*)(xr + 4);
                float vv[8] = {v0.x, v0.y, v0.z, v0.w, v1.x, v1.y, v1.z, v1.w};
#pragma unroll
                for (int j = 0; j < 8; ++j) {
                    float v = vv[j];
                    if (applyAct) v = fmaxf(v * scale[c + j] + shift[c + j], 0.f);
                    f2bf_split(v, h[j], l[j]);
                }
            } else {
#pragma unroll
                for (int j = 0; j < 8; ++j) { h[j] = 0; l[j] = 0; }
            }
            *(ushort4*)&sAh[r * PITCH + lc] = make_ushort4(h[0], h[1], h[2], h[3]);
            *(ushort4*)&sAh[r * PITCH + lc + 4] = make_ushort4(h[4], h[5], h[6], h[7]);
            *(ushort4*)&sAl[r * PITCH + lc] = make_ushort4(l[0], l[1], l[2], l[3]);
            *(ushort4*)&sAl[r * PITCH + lc + 4] = make_ushort4(l[4], l[5], l[6], l[7]);
        }
#pragma unroll
        for (int it = 0; it < 2; ++it) {
            int r = lr + it * 64;
            int c = k0 + lc;
            int o = o0 + r;
            uint4 vh = {0, 0, 0, 0}, vl = {0, 0, 0, 0};
            if (o < O && c < CPW) {
                size_t goff = (size_t)o * CPW + c;
                vh = *(const uint4*)(Bh + goff);
                vl = *(const uint4*)(Bl + goff);
            }
            *(uint4*)&sBh[r * PITCH + lc] = vh;
            *(uint4*)&sBl[r * PITCH + lc] = vl;
        }
        __syncthreads();
        s16x8 ah[4], al[4], bh[4], bl[4];
#pragma unroll
        for (int mt = 0; mt < 4; ++mt) {
            int rowoff = (wm + mt * 16 + col15) * PITCH + quad * 8;
            ah[mt] = *(const s16x8*)&sAh[rowoff];
            al[mt] = *(const s16x8*)&sAl[rowoff];
        }
#pragma unroll
        for (int ot = 0; ot < 4; ++ot) {
            int rowoff = (wo + ot * 16 + col15) * PITCH + quad * 8;
            bh[ot] = *(const s16x8*)&sBh[rowoff];
            bl[ot] = *(const s16x8*)&sBl[rowoff];
        }
#pragma unroll
        for (int mt = 0; mt < 4; ++mt)
#pragma unroll
            for (int ot = 0; ot < 4; ++ot) {
                acc[mt][ot] = __builtin_amdgcn_mfma_f32_16x16x32_bf16(
                    ah[mt], bl[ot], acc[mt][ot], 0, 0, 0);
                acc[mt][ot] = __builtin_amdgcn_mfma_f32_16x16x32_bf16(
                    al[mt], bh[ot], acc[mt][ot], 0, 0, 0);
                acc[mt][ot] = __builtin_amdgcn_mfma_f32_16x16x32_bf16(
                    ah[mt], bh[ot], acc[mt][ot], 0, 0, 0);
            }
        __syncthreads();
    }
#pragma unroll
    for (int mt = 0; mt < 4; ++mt)
#pragma unroll
        for (int ot = 0; ot < 4; ++ot) {
            int og = o0 + wo + ot * 16 + col15;
            if (og < O) {
#pragma unroll
                for (int r = 0; r < 4; ++r) {
                    int mg = m0 + wm + mt * 16 + quad * 4 + r;
                    Y[(size_t)mg * O + og] = acc[mt][ot][r];
                }
            }
        }
    // BN stats epilogue (deterministic fixed-order combine; R13-identical).
#pragma unroll
    for (int ot = 0; ot < 4; ++ot) {
        float s = 0.f, s2 = 0.f;
#pragma unroll
        for (int mt = 0; mt < 4; ++mt)
#pragma unroll
            for (int r = 0; r < 4; ++r) {
                float v = acc[mt][ot][r];
                s += v;
                s2 += v * v;
            }
        int slot = ((wid * 4 + quad) * 16 + col15) * 4 + ot;
        sred[slot * 2] = s;
        sred[slot * 2 + 1] = s2;
    }
    __syncthreads();
    if (tid < 128) {
        int col = tid;
        int o = o0 + col;
        if (o < O) {
            int cb = col >> 6;
            int ot = (col & 63) >> 4;
            int c15 = col & 15;
            double S = 0.0, S2 = 0.0;
#pragma unroll
            for (int wp = 0; wp < 2; ++wp) {
                int wd = cb + wp * 2;
#pragma unroll
                for (int q = 0; q < 4; ++q) {
                    int slot = ((wd * 4 + q) * 16 + c15) * 4 + ot;
                    S += (double)sred[slot * 2];
                    S2 += (double)sred[slot * 2 + 1];
                }
            }
            part[(size_t)o * YB + blockIdx.x] = S;
            part[(size_t)O * YB + (size_t)o * YB + blockIdx.x] = S2;
        }
    }

    // ---- last-block-done finalize (replaces finalize_bn dispatch) ----
    __threadfence();                       // release part writes (device scope)
    if (tid == 0) {
        unsigned prev = atomicAdd(counter, 1u);
        sLast = (prev == gridDim.x * gridDim.y - 1u) ? 1 : 0;
    }
    __syncthreads();
    if (sLast) {
        // all other blocks' part writes are visible (their fence ordered the
        // writes before their ticket; our ticket read them all).
        for (int o = tid; o < O; o += 256) {
            const double* ps = part + (size_t)o * YB;
            const double* pq = part + (size_t)O * YB + (size_t)o * YB;
            double s0 = 0.0, s1 = 0.0, s2a = 0.0, s3 = 0.0;
            double q0 = 0.0, q1 = 0.0, q2 = 0.0, q3 = 0.0;
            for (int yb = 0; yb < YB; yb += 4) {   // YB is always a mult of 4
                s0 += ps[yb];     s1 += ps[yb + 1];
                s2a += ps[yb + 2]; s3 += ps[yb + 3];
                q0 += pq[yb];     q1 += pq[yb + 1];
                q2 += pq[yb + 2]; q3 += pq[yb + 3];
            }
            double S = (s0 + s1) + (s2a + s3);
            double S2 = (q0 + q1) + (q2 + q3);
            double mean = S * invM;
            double var = S2 * invM - mean * mean;
            float varf = (float)var;
            if (varf < 0.f) varf = 0.f;
            float sc = gvec[o] * rsqrtf(varf + 1e-5f);
            scOut[o] = sc;
            shOut[o] = bvec[o] - (float)mean * sc;
        }
    }
}

// ---------------- BN + ReLU + max over K (+ optional SA2 query_ball) -------
__global__ __launch_bounds__(256) void bn_relu_max(
    const float* __restrict__ Y, const float* __restrict__ scale,
    const float* __restrict__ shift, float* __restrict__ out,
    int Stot, int K, int O, int nMain,
    const float* __restrict__ qbXyz, const float* __restrict__ qbCtr,
    int* __restrict__ qbOut)
{
    if ((int)blockIdx.x >= nMain) {   // piggyback: SA2 query_ball (4 waves)
        int wid = threadIdx.x >> 6, lane = threadIdx.x & 63;
        int gw = ((int)blockIdx.x - nMain) * 4 + wid;
        if (gw < 1024) qb2_dev(qbXyz, qbCtr, qbOut, gw, lane);
        return;
    }
    int idx = blockIdx.x * 256 + threadIdx.x;
    if (idx >= Stot * O) return;
    int s = idx / O;
    int o = idx - s * O;
    const float* basep = Y + (size_t)s * K * O + o;
    float sc = scale[o], sh = shift[o];
    float mx = 0.f;
    for (int k = 0; k < K; ++k) {
        float v = basep[(size_t)k * O] * sc + sh;
        v = fmaxf(v, 0.f);
        mx = fmaxf(mx, v);
    }
    out[idx] = mx;
}

// ============================================================================
extern "C" void kernel_launch(void* const* d_in, const int* in_sizes, int n_in,
                              void* d_out, int out_size, void* d_ws, size_t ws_size,
                              hipStream_t stream)
{
    const float* xin = (const float*)d_in[0];
    const float* w[9]; const float* g[9]; const float* bb[9];
    for (int i = 0; i < 9; ++i) {
        w[i]  = (const float*)d_in[1 + 3 * i];
        g[i]  = (const float*)d_in[2 + 3 * i];
        bb[i] = (const float*)d_in[3 + 3 * i];
    }

    char* base = (char*)d_ws;
    size_t off = 0;
    auto alloc = [&](size_t bytes) -> void* {
        void* p = base + off;
        off = (off + bytes + 255) & ~(size_t)255;
        return p;
    };
    const int OC[9][3] = {{64,4,8},{64,64,64},{128,64,64},
                          {128,131,136},{128,128,128},{256,128,128},
                          {256,259,264},{512,256,256},{1024,512,512}};
    size_t woff[10]; woff[0] = 0;
    for (int i = 0; i < 9; ++i) woff[i + 1] = woff[i] + (size_t)OC[i][0] * OC[i][2];

    // --- small / metadata region (memset-protected) ---
    int*    fps1   = (int*)alloc((size_t)4096 * 4);
    int*    fps2   = (int*)alloc((size_t)1024 * 4);
    int*    qb2    = (int*)alloc((size_t)65536 * 4);
    float*  nx1    = (float*)alloc((size_t)12288 * 4);
    float*  nx2    = (float*)alloc((size_t)3072 * 4);
    float*  feat1  = (float*)alloc((size_t)524288 * 4);
    float*  feat2  = (float*)alloc((size_t)262144 * 4);
    double* part   = (double*)alloc((size_t)262144 * 8);
    float*  scales = (float*)alloc((size_t)9 * 1024 * 4);
    float*  shifts = (float*)alloc((size_t)9 * 1024 * 4);
    unsigned* ctrs = (unsigned*)alloc((size_t)16 * 4);   // per-layer tickets
    unsigned short* WH = (unsigned short*)alloc(woff[9] * 2);
    unsigned short* WL = (unsigned short*)alloc(woff[9] * 2);
    const size_t zeroBytes = off;
    // --- big ping/pong buffers (fully written before read at every use) ---
    float*  XG = (float*)alloc((size_t)65536 * 136 * 4);
    float*  A  = (float*)alloc((size_t)16777216 * 4);
    if (off > ws_size) return;

    // Defensive zero of the metadata region only (~5 MB): indices, stats,
    // and the atomic tickets start at 0 every invocation.
    hipMemsetAsync(d_ws, 0, zeroBytes, stream);

    PWArgs pwa;
    for (int i = 0; i < 9; ++i) {
        pwa.w[i] = w[i]; pwa.off[i] = (unsigned)woff[i];
        pwa.O[i] = OC[i][0]; pwa.C[i] = OC[i][1]; pwa.CP[i] = OC[i][2];
    }
    const int nPrep = (int)((woff[9] + 255) / 256);

    auto gemm = [&](const float* X, const float* sc, const float* sh, int act,
                    int wi, float* Y, int YB, int OB, int AC, int CPW, int O,
                    int li, double invM) {
        gemm_fused<<<dim3(YB, OB), 256, 0, stream>>>(
            X, sc, sh, act, WH + woff[wi], WL + woff[wi], Y, part,
            AC, CPW, O, g[wi], bb[wi], scales + li * 1024, shifts + li * 1024,
            invM, ctrs + li);
    };

    // ---------------- SA1 ----------------
    fps_block<256, 16, 4><<<8 + nPrep, 256, 0, stream>>>(
        xin, 512, fps1, nx1, 8, pwa, WH, WL, (int)woff[9]);
    // qb_group1 blocks 0-1023: group; 1024-1031: SA2 single-wave FPS.
    qb_group1<<<1024 + 8, 256, 0, stream>>>(xin, nx1, XG, 1024, nx1, fps2, nx2);

    gemm(XG, nullptr, nullptr, 0, 0, A, 1024, 1, 8, 8, 64, 0, 1.0 / 131072.0);
    gemm(A, scales + 0, shifts + 0, 1, 1, XG, 1024, 1, 64, 64, 64, 1, 1.0 / 131072.0);
    gemm(XG, scales + 1024, shifts + 1024, 1, 2, A, 1024, 1, 64, 64, 128, 2, 1.0 / 131072.0);
    // bn_relu_max (2048 blocks) + SA2 query_ball (256 blocks) fused.
    bn_relu_max<<<2048 + 256, 256, 0, stream>>>(
        A, scales + 2048, shifts + 2048, feat1, 4096, 32, 128, 2048,
        nx1, nx2, qb2);

    // ---------------- SA2 ----------------
    group2_kernel<<<(65536 * 136) / 256, 256, 0, stream>>>(nx1, feat1, qb2, nx2, XG);
    gemm(XG, nullptr, nullptr, 0, 3, A, 512, 1, 136, 136, 128, 3, 1.0 / 65536.0);
    gemm(A, scales + 3072, shifts + 3072, 1, 4, XG, 512, 1, 128, 128, 128, 4, 1.0 / 65536.0);
    gemm(XG, scales + 4096, shifts + 4096, 1, 5, A, 512, 2, 128, 128, 256, 5, 1.0 / 65536.0);
    bn_relu_max<<<(1024 * 256) / 256, 256, 0, stream>>>(
        A, scales + 5120, shifts + 5120, feat2, 1024, 64, 256, 1024 * 256 / 256,
        nullptr, nullptr, nullptr);

    // ---------------- SA3 (group_all) ----------------
    group3_kernel<<<(1024 * 264 + 255) / 256, 256, 0, stream>>>(nx2, feat2, XG);
    gemm(XG, nullptr, nullptr, 0, 6, A, 8, 2, 264, 264, 256, 6, 1.0 / 1024.0);
    gemm(A, scales + 6144, shifts + 6144, 1, 7, XG, 8, 4, 256, 256, 512, 7, 1.0 / 1024.0);
    gemm(XG, scales + 7168, shifts + 7168, 1, 8, A, 8, 8, 512, 512, 1024, 8, 1.0 / 1024.0);
    bn_relu_max<<<(8 * 1024) / 256, 256, 0, stream>>>(
        A, scales + 8192, shifts + 8192, (float*)d_out, 8, 128, 1024,
        (8 * 1024) / 256, nullptr, nullptr, nullptr);
}

// Round 8
// 1745.141 us; speedup vs baseline: 1.0412x; 1.0412x over previous
//
#include <hip/hip_runtime.h>

// ============================================================================
// TemporalPointNet (PointNet++ style) forward on MI355X.
// B=2, T=4 -> BT=8 "batches", N=4096 points, 4 coords (xyz + t).
// SA1: npoint=512, r=0.2, K=32, C_in=4,  MLP 64,64,128
// SA2: npoint=128, r=0.4, K=64, C_in=131, MLP 128,128,256
// SA3: group_all,          K=128, C_in=259, MLP 256,512,1024
//
// R19: fence-free finalize fusion. R18's last-block finalize was correct but
// used per-block __threadfence() -> on multi-XCD gfx950 that's a per-block
// L2 WRITEBACK (per-XCD L2s non-coherent): gemms +110us each, total 1817us.
// R19 keeps the fusion with a coherent-point handoff instead:
//  - part written via agent-scope RELAXED atomic stores (sc1: write-through
//    to coherent point; no L2 flush).
//  - __syncthreads() before the ticket: its emitted s_waitcnt vmcnt(0)
//    (m97-verified) completes all waves' part stores at the coherent point.
//  - ticket = RELAXED agent-scope fetch_add (executes at coherent point;
//    no release fence, no buffer_wbl2/inv anywhere).
//  - last block reads part via agent-scope relaxed atomic loads and
//    finalizes with TPC=256/O threads/channel (fixed-order LDS combine,
//    deterministic double; reorder ~1e-13 << 0.123 threshold).
//  - Y / scales / shifts stay normal stores (consumed next dispatch only;
//    kernel-boundary flush provides coherence once, not per block).
// Keeps: R13 gemm math bit-identical; prep_w piggyback in fps_block;
// fps_wave piggyback in qb_group1; bn_relu_max+SA2-query_ball fusion.
// FPS critical chains byte-identical to R11/R13 measured-best (286us).
// Dispatches: 17.
// ============================================================================

typedef short s16x8 __attribute__((ext_vector_type(8)));
typedef float f32x4 __attribute__((ext_vector_type(4)));

__device__ __forceinline__ unsigned short f2bf_rne(float f) {
    unsigned u = __float_as_uint(f);
    u += 0x7FFFu + ((u >> 16) & 1u);
    return (unsigned short)(u >> 16);
}
// split f32 -> (hi, lo) bf16 pair: hi = rne(v), lo = rne(v - hi)
__device__ __forceinline__ void f2bf_split(float v, unsigned short& hi,
                                           unsigned short& lo) {
    unsigned u = __float_as_uint(v);
    unsigned r = u + 0x7FFFu + ((u >> 16) & 1u);
    hi = (unsigned short)(r >> 16);
    float vh = __uint_as_float(r & 0xFFFF0000u);
    lo = f2bf_rne(v - vh);
}

__device__ __forceinline__ unsigned long long umax64(unsigned long long a,
                                                     unsigned long long b) {
    return a > b ? a : b;
}

// Wave64 max-reduce via DPP: 1 DPP + 1 max per step (R9 measured-best;
// R10/R12 variants regressed — do not touch).
__device__ __forceinline__ unsigned wred_umax63(unsigned v) {
    unsigned t;
    t = (unsigned)__builtin_amdgcn_update_dpp(0, (int)v, 0x111, 0xf, 0xf, true); if (t > v) v = t;
    t = (unsigned)__builtin_amdgcn_update_dpp(0, (int)v, 0x112, 0xf, 0xf, true); if (t > v) v = t;
    t = (unsigned)__builtin_amdgcn_update_dpp(0, (int)v, 0x114, 0xf, 0xf, true); if (t > v) v = t;
    t = (unsigned)__builtin_amdgcn_update_dpp(0, (int)v, 0x118, 0xf, 0xf, true); if (t > v) v = t;
    t = (unsigned)__builtin_amdgcn_update_dpp(0, (int)v, 0x142, 0xa, 0xf, true); if (t > v) v = t;
    t = (unsigned)__builtin_amdgcn_update_dpp(0, (int)v, 0x143, 0xc, 0xf, true); if (t > v) v = t;
    return v;
}

// Wave argmax of (dist, min-index). Exact first-occurrence argmax.
__device__ __forceinline__ void wave_argmax(unsigned dbits, unsigned nInv,
                                            unsigned& vmax, unsigned& iInv) {
    unsigned m = wred_umax63(dbits);
    vmax = (unsigned)__builtin_amdgcn_readlane((int)m, 63);
    unsigned cand = (dbits == vmax) ? nInv : 0u;
    unsigned im = wred_umax63(cand);
    iInv = (unsigned)__builtin_amdgcn_readlane((int)im, 63);
}

// ---------------- all-layer weight pre-split (device body) ----------------
struct PWArgs {
    const float* w[9];
    unsigned off[9];
    int O[9], C[9], CP[9];
};
__device__ __forceinline__ void prep_w_dev(const PWArgs& a,
                                           unsigned short* __restrict__ wh,
                                           unsigned short* __restrict__ wl,
                                           int i) {
    int l = 0;
#pragma unroll
    for (int k = 1; k < 9; ++k) if (i >= (int)a.off[k]) l = k;
    int li = i - (int)a.off[l];
    int CP = a.CP[l];
    int o = li / CP;
    int c = li - o * CP;
    float v = (c < a.C[l]) ? a.w[l][(size_t)o * a.C[l] + c] : 0.f;
    unsigned short h, lo;
    f2bf_split(v, h, lo);
    wh[i] = h; wl[i] = lo;
}

// ---------------- FPS (multi-wave): one block (NT thr) per batch ------------
// R7/R9 structure (measured best 286us). Blocks >= nFps run the weight
// pre-split (fully hidden in the FPS shadow).
template<int NT, int ITEMS, int STRIDE>
__global__ __launch_bounds__(NT) void fps_block(
    const float* __restrict__ pts, int npoint,
    int* __restrict__ outIdx, float* __restrict__ outXyz,
    int nFps, PWArgs pw, unsigned short* __restrict__ wh,
    unsigned short* __restrict__ wl, int wtotal)
{
    constexpr int N = NT * ITEMS;
    constexpr int NW = NT / 64;
    __shared__ float4 scoord[N];
    __shared__ unsigned long long wkey[2][NW];

    if (blockIdx.x >= nFps) {   // piggyback: weight split on idle CUs
        int i = (blockIdx.x - nFps) * NT + threadIdx.x;
        if (i < wtotal) prep_w_dev(pw, wh, wl, i);
        return;
    }

    const int b = blockIdx.x;
    const int tid = threadIdx.x;
    const int wid = tid >> 6;
    const int lane = tid & 63;
    const float* P = pts + (size_t)b * N * STRIDE;

    float px[ITEMS], py[ITEMS], pz[ITEMS], dloc[ITEMS];
#pragma unroll
    for (int w = 0; w < ITEMS; ++w) {
        int n = tid + w * NT;
        float x, y, z;
        if (STRIDE == 4) {
            float4 v = *(const float4*)(P + (size_t)n * 4);
            x = v.x; y = v.y; z = v.z;
        } else {
            x = P[(size_t)n * STRIDE + 0];
            y = P[(size_t)n * STRIDE + 1];
            z = P[(size_t)n * STRIDE + 2];
        }
        px[w] = x; py[w] = y; pz[w] = z;
        scoord[n] = make_float4(x, y, z, 0.f);
        dloc[w] = 1e10f;
    }
    __syncthreads();
    float4 c0 = scoord[0];
    float cx = c0.x, cy = c0.y, cz = c0.z;
    int far = 0;

    for (int i = 0; i < npoint; ++i) {
        if (tid == 0) {
            outIdx[(size_t)b * npoint + i] = far;
            outXyz[((size_t)b * npoint + i) * 3 + 0] = cx;
            outXyz[((size_t)b * npoint + i) * 3 + 1] = cy;
            outXyz[((size_t)b * npoint + i) * 3 + 2] = cz;
        }
        float bestV = -1.0f;
        int bestW = 0;
#pragma unroll
        for (int w = 0; w < ITEMS; ++w) {
            float dx = __fsub_rn(px[w], cx);
            float dy = __fsub_rn(py[w], cy);
            float dz = __fsub_rn(pz[w], cz);
            float d = __fadd_rn(__fadd_rn(__fmul_rn(dx, dx), __fmul_rn(dy, dy)),
                                __fmul_rn(dz, dz));
            float dd = fminf(dloc[w], d);
            dloc[w] = dd;
            if (dd > bestV) { bestV = dd; bestW = w; }  // strict > : lowest w kept
        }
        int bestN = tid + bestW * NT;   // n grows with w -> min n on tie
        unsigned vmax, iInv;
        wave_argmax(__float_as_uint(bestV), 0xFFFFFFFFu ^ (unsigned)bestN,
                    vmax, iInv);
        const int par = i & 1;
        if (lane == 0)
            wkey[par][wid] = ((unsigned long long)vmax << 32) | iInv;
        __syncthreads();   // single barrier per iteration (parity dbuf)
        unsigned long long kb = wkey[par][0];
#pragma unroll
        for (int w2 = 1; w2 < NW; ++w2) kb = umax64(kb, wkey[par][w2]);
        far = (int)(0xFFFFFFFFu ^ (unsigned)kb);
        float4 cc = scoord[far];   // broadcast, conflict-free
        cx = cc.x; cy = cc.y; cz = cc.z;
    }
}

// ---------------- FPS (single wave, device body, no barriers) ---------------
__device__ void fps_wave_dev(const float* __restrict__ pts, int npoint,
                             int* __restrict__ outIdx, float* __restrict__ outXyz,
                             int b, float4* scoord)
{
    constexpr int ITEMS = 8;
    constexpr int STRIDE = 3;
    constexpr int N = 64 * ITEMS;
    const int tid = threadIdx.x;   // 0..63
    const float* P = pts + (size_t)b * N * STRIDE;

    float px[ITEMS], py[ITEMS], pz[ITEMS], dloc[ITEMS];
#pragma unroll
    for (int w = 0; w < ITEMS; ++w) {
        int n = tid + w * 64;
        float x = P[(size_t)n * STRIDE + 0];
        float y = P[(size_t)n * STRIDE + 1];
        float z = P[(size_t)n * STRIDE + 2];
        px[w] = x; py[w] = y; pz[w] = z;
        scoord[n] = make_float4(x, y, z, 0.f);
        dloc[w] = 1e10f;
    }
    __threadfence_block();
    float4 c0 = scoord[0];
    float cx = c0.x, cy = c0.y, cz = c0.z;
    int far = 0;

    for (int i = 0; i < npoint; ++i) {
        if (tid == 0) {
            outIdx[(size_t)b * npoint + i] = far;
            outXyz[((size_t)b * npoint + i) * 3 + 0] = cx;
            outXyz[((size_t)b * npoint + i) * 3 + 1] = cy;
            outXyz[((size_t)b * npoint + i) * 3 + 2] = cz;
        }
        float bestV = -1.0f;
        int bestW = 0;
#pragma unroll
        for (int w = 0; w < ITEMS; ++w) {
            float dx = __fsub_rn(px[w], cx);
            float dy = __fsub_rn(py[w], cy);
            float dz = __fsub_rn(pz[w], cz);
            float d = __fadd_rn(__fadd_rn(__fmul_rn(dx, dx), __fmul_rn(dy, dy)),
                                __fmul_rn(dz, dz));
            float dd = fminf(dloc[w], d);
            dloc[w] = dd;
            if (dd > bestV) { bestV = dd; bestW = w; }
        }
        int bestN = tid + bestW * 64;
        unsigned vmax, iInv;
        wave_argmax(__float_as_uint(bestV), 0xFFFFFFFFu ^ (unsigned)bestN,
                    vmax, iInv);
        far = (int)(0xFFFFFFFFu ^ iInv);
        float4 cc = scoord[far];
        cx = cc.x; cy = cc.y; cz = cc.z;
    }
}

// ---------------- fused query_ball + group for SA1 (+fps_wave piggyback) ----
__global__ __launch_bounds__(256) void qb_group1(
    const float* __restrict__ xyz /*(8,4096,4)*/,
    const float* __restrict__ ctr /*(8*512,3)*/,
    float* __restrict__ out /*(8*512*32, 8)*/,
    int nQb, const float* __restrict__ fpsPts,
    int* __restrict__ fpsIdx, float* __restrict__ fpsXyz)
{
    __shared__ float4 scoord[512];
    if ((int)blockIdx.x >= nQb) {   // piggyback: single-wave FPS (SA2)
        if (threadIdx.x < 64)
            fps_wave_dev(fpsPts, 128, fpsIdx, fpsXyz,
                         (int)blockIdx.x - nQb, scoord);
        return;
    }
    int gw = (blockIdx.x * 256 + threadIdx.x) >> 6;
    int lane = threadIdx.x & 63;
    if (gw >= 4096) return;
    int b = gw >> 9;
    const float* P = xyz + (size_t)b * 4096 * 4;
    float cx = ctr[(size_t)gw * 3 + 0];
    float cy = ctr[(size_t)gw * 3 + 1];
    float cz = ctr[(size_t)gw * 3 + 2];
    float* out0 = out + (size_t)gw * 32 * 8;
    int cnt = 0;
    float f0x = 0.f, f0y = 0.f, f0z = 0.f, f0t = 0.f;
    bool haveFirst = false;
    for (int base = 0; base < 4096 && cnt < 32; base += 64) {
        int n = base + lane;
        float4 p = *(const float4*)(P + (size_t)n * 4);
        float ex = __fsub_rn(p.x, cx);
        float ey = __fsub_rn(p.y, cy);
        float ez = __fsub_rn(p.z, cz);
        float d = __fadd_rn(__fadd_rn(__fmul_rn(ex, ex), __fmul_rn(ey, ey)),
                            __fmul_rn(ez, ez));
        bool inb = !(d > 0.04f);
        unsigned long long mask = __ballot(inb);
        if (mask) {
            if (!haveFirst) {
                int fl = (int)__builtin_ctzll(mask);   // wave-uniform
                f0x = __shfl(ex, fl); f0y = __shfl(ey, fl);
                f0z = __shfl(ez, fl); f0t = __shfl(p.w, fl);
                haveFirst = true;
            }
            if (inb) {
                int pos = cnt + __builtin_popcountll(mask & ((1ull << lane) - 1ull));
                if (pos < 32) {
                    float* o = out0 + (size_t)pos * 8;
                    *(float4*)o = make_float4(ex, ey, ez, p.w);
                    *(float4*)(o + 4) = make_float4(0.f, 0.f, 0.f, 0.f);
                }
            }
            cnt += (int)__builtin_popcountll(mask);
        }
    }
    if (cnt > 32) cnt = 32;
    for (int p2 = cnt + lane; p2 < 32; p2 += 64) {
        float* o = out0 + (size_t)p2 * 8;
        *(float4*)o = make_float4(f0x, f0y, f0z, f0t);
        *(float4*)(o + 4) = make_float4(0.f, 0.f, 0.f, 0.f);
    }
}

// ---------------- query_ball body (SA2 geometry, device) ----------------
__device__ __forceinline__ void qb2_dev(
    const float* __restrict__ xyz, const float* __restrict__ centers,
    int* __restrict__ outIdx, int gw, int lane)
{
    const int N = 512, stride = 3, S = 128, nsample = 64;
    const float r2 = 0.16f;
    int b = gw / S;
    const float* P = xyz + (size_t)b * N * stride;
    float cx = centers[(size_t)gw * 3 + 0];
    float cy = centers[(size_t)gw * 3 + 1];
    float cz = centers[(size_t)gw * 3 + 2];
    int* out = outIdx + (size_t)gw * nsample;
    int cnt = 0;
    int firstIdx = 0;
    bool haveFirst = false;
    for (int base = 0; base < N && cnt < nsample; base += 64) {
        int n = base + lane;
        bool inb = false;
        if (n < N) {
            float dx = __fsub_rn(cx, P[(size_t)n * stride + 0]);
            float dy = __fsub_rn(cy, P[(size_t)n * stride + 1]);
            float dz = __fsub_rn(cz, P[(size_t)n * stride + 2]);
            float d = __fadd_rn(__fadd_rn(__fmul_rn(dx, dx), __fmul_rn(dy, dy)),
                                __fmul_rn(dz, dz));
            inb = !(d > r2);
        }
        unsigned long long mask = __ballot(inb);
        if (mask) {
            if (!haveFirst) { firstIdx = base + __builtin_ctzll(mask); haveFirst = true; }
            if (inb) {
                int pos = cnt + __builtin_popcountll(mask & ((1ull << lane) - 1ull));
                if (pos < nsample) out[pos] = n;
            }
            cnt += (int)__builtin_popcountll(mask);
        }
    }
    if (cnt > nsample) cnt = nsample;
    for (int p = cnt + lane; p < nsample; p += 64) out[p] = firstIdx;
}

// ---------------- grouping kernels (f32, padded rows) ----------------------
__global__ __launch_bounds__(256) void group2_kernel(
    const float* __restrict__ xyz, const float* __restrict__ feat,
    const int* __restrict__ qb, const float* __restrict__ ctr,
    float* __restrict__ out)
{
    int i = blockIdx.x * 256 + threadIdx.x;
    if (i >= 65536 * 136) return;
    int sk = i / 136;
    int c = i - sk * 136;
    int b = sk / (128 * 64);
    int bs = sk / 64;
    int idx = qb[sk];
    idx = (idx < 0) ? 0 : (idx > 511 ? 511 : idx);
    float v = 0.f;
    if (c < 3)        v = __fsub_rn(xyz[((size_t)b * 512 + idx) * 3 + c], ctr[(size_t)bs * 3 + c]);
    else if (c < 131) v = feat[((size_t)b * 512 + idx) * 128 + (c - 3)];
    out[i] = v;
}

__global__ __launch_bounds__(256) void group3_kernel(
    const float* __restrict__ ctr2, const float* __restrict__ feat2,
    float* __restrict__ out)
{
    int i = blockIdx.x * 256 + threadIdx.x;
    if (i >= 1024 * 264) return;
    int sk = i / 264;
    int c = i - sk * 264;
    float v = 0.f;
    if (c < 3)        v = ctr2[(size_t)sk * 3 + c];
    else if (c < 259) v = feat2[(size_t)sk * 256 + (c - 3)];
    out[i] = v;
}

// ---------------- fused GEMM: Y = act(X) * W^T + BN stats + finalize -------
// R13 body (bit-identical math). One 128x128 tile per block, grid (YB, OB).
// Fence-free last-block finalize: part via agent-scope relaxed atomic
// stores (coherent point); __syncthreads' vmcnt(0) completes them before the
// relaxed agent-scope ticket; last block reads part via agent-scope loads.
__global__ __launch_bounds__(256) void gemm_fused(
    const float* __restrict__ X,
    const float* __restrict__ scale, const float* __restrict__ shift,
    int applyAct,
    const unsigned short* __restrict__ Bh, const unsigned short* __restrict__ Bl,
    float* __restrict__ Y, double* __restrict__ part,
    int AC, int CPW, int O,
    const float* __restrict__ gvec, const float* __restrict__ bvec,
    float* __restrict__ scOut, float* __restrict__ shOut,
    double invM, unsigned* __restrict__ counter)
{
    constexpr int PITCH = 40;
    __shared__ __align__(16) unsigned short sAh[128 * PITCH];
    __shared__ __align__(16) unsigned short sAl[128 * PITCH];
    __shared__ __align__(16) unsigned short sBh[128 * PITCH];
    __shared__ __align__(16) unsigned short sBl[128 * PITCH];
    __shared__ __align__(16) float sred[2048];
    __shared__ int sLast;

    const int tid = threadIdx.x;
    const int lane = tid & 63;
    const int wid = tid >> 6;
    const int col15 = lane & 15;
    const int quad = lane >> 4;
    const int wm = (wid >> 1) * 64;
    const int wo = (wid & 1) * 64;
    const int m0 = blockIdx.x * 128;
    const int o0 = blockIdx.y * 128;
    const int YB = gridDim.x;
    const int lr = tid >> 2;
    const int lc = (tid & 3) * 8;

    f32x4 acc[4][4];
#pragma unroll
    for (int mt = 0; mt < 4; ++mt)
#pragma unroll
        for (int ot = 0; ot < 4; ++ot)
            acc[mt][ot] = {0.f, 0.f, 0.f, 0.f};

    for (int k0 = 0; k0 < CPW; k0 += 32) {
#pragma unroll
        for (int it = 0; it < 2; ++it) {
            int r = lr + it * 64;
            int c = k0 + lc;
            unsigned short h[8], l[8];
            if (c + 8 <= AC) {
                const float* xr = X + (size_t)(m0 + r) * AC + c;
                float4 v0 = *(const float4*)xr;
                float4 v1 = *(const float4*)(xr + 4);
                float vv[8] = {v0.x, v0.y, v0.z, v0.w, v1.x, v1.y, v1.z, v1.w};
#pragma unroll
                for (int j = 0; j < 8; ++j) {
                    float v = vv[j];
                    if (applyAct) v = fmaxf(v * scale[c + j] + shift[c + j], 0.f);
                    f2bf_split(v, h[j], l[j]);
                }
            } else {
#pragma unroll
                for (int j = 0; j < 8; ++j) { h[j] = 0; l[j] = 0; }
            }
            *(ushort4*)&sAh[r * PITCH + lc] = make_ushort4(h[0], h[1], h[2], h[3]);
            *(ushort4*)&sAh[r * PITCH + lc + 4] = make_ushort4(h[4], h[5], h[6], h[7]);
            *(ushort4*)&sAl[r * PITCH + lc] = make_ushort4(l[0], l[1], l[2], l[3]);
            *(ushort4*)&sAl[r * PITCH + lc + 4] = make_ushort4(l[4], l[5], l[6], l[7]);
        }
#pragma unroll
        for (int it = 0; it < 2; ++it) {
            int r = lr + it * 64;
            int c = k0 + lc;
            int o = o0 + r;
            uint4 vh = {0, 0, 0, 0}, vl = {0, 0, 0, 0};
            if (o < O && c < CPW) {
                size_t goff = (size_t)o * CPW + c;
                vh = *(const uint4*)(Bh + goff);
                vl = *(const uint4*)(Bl + goff);
            }
            *(uint4*)&sBh[r * PITCH + lc] = vh;
            *(uint4*)&sBl[r * PITCH + lc] = vl;
        }
        __syncthreads();
        s16x8 ah[4], al[4], bh[4], bl[4];
#pragma unroll
        for (int mt = 0; mt < 4; ++mt) {
            int rowoff = (wm + mt * 16 + col15) * PITCH + quad * 8;
            ah[mt] = *(const s16x8*)&sAh[rowoff];
            al[mt] = *(const s16x8*)&sAl[rowoff];
        }
#pragma unroll
        for (int ot = 0; ot < 4; ++ot) {
            int rowoff = (wo + ot * 16 + col15) * PITCH + quad * 8;
            bh[ot] = *(const s16x8*)&sBh[rowoff];
            bl[ot] = *(const s16x8*)&sBl[rowoff];
        }
#pragma unroll
        for (int mt = 0; mt < 4; ++mt)
#pragma unroll
            for (int ot = 0; ot < 4; ++ot) {
                acc[mt][ot] = __builtin_amdgcn_mfma_f32_16x16x32_bf16(
                    ah[mt], bl[ot], acc[mt][ot], 0, 0, 0);
                acc[mt][ot] = __builtin_amdgcn_mfma_f32_16x16x32_bf16(
                    al[mt], bh[ot], acc[mt][ot], 0, 0, 0);
                acc[mt][ot] = __builtin_amdgcn_mfma_f32_16x16x32_bf16(
                    ah[mt], bh[ot], acc[mt][ot], 0, 0, 0);
            }
        __syncthreads();
    }
#pragma unroll
    for (int mt = 0; mt < 4; ++mt)
#pragma unroll
        for (int ot = 0; ot < 4; ++ot) {
            int og = o0 + wo + ot * 16 + col15;
            if (og < O) {
#pragma unroll
                for (int r = 0; r < 4; ++r) {
                    int mg = m0 + wm + mt * 16 + quad * 4 + r;
                    Y[(size_t)mg * O + og] = acc[mt][ot][r];
                }
            }
        }
    // BN stats epilogue (deterministic fixed-order combine; R13-identical).
#pragma unroll
    for (int ot = 0; ot < 4; ++ot) {
        float s = 0.f, s2 = 0.f;
#pragma unroll
        for (int mt = 0; mt < 4; ++mt)
#pragma unroll
            for (int r = 0; r < 4; ++r) {
                float v = acc[mt][ot][r];
                s += v;
                s2 += v * v;
            }
        int slot = ((wid * 4 + quad) * 16 + col15) * 4 + ot;
        sred[slot * 2] = s;
        sred[slot * 2 + 1] = s2;
    }
    __syncthreads();
    if (tid < 128) {
        int col = tid;
        int o = o0 + col;
        if (o < O) {
            int cb = col >> 6;
            int ot = (col & 63) >> 4;
            int c15 = col & 15;
            double S = 0.0, S2 = 0.0;
#pragma unroll
            for (int wp = 0; wp < 2; ++wp) {
                int wd = cb + wp * 2;
#pragma unroll
                for (int q = 0; q < 4; ++q) {
                    int slot = ((wd * 4 + q) * 16 + c15) * 4 + ot;
                    S += (double)sred[slot * 2];
                    S2 += (double)sred[slot * 2 + 1];
                }
            }
            // coherent-point (agent-scope) stores: visible to the last
            // block without any L2 writeback fence.
            __hip_atomic_store(&part[(size_t)o * YB + blockIdx.x], S,
                               __ATOMIC_RELAXED, __HIP_MEMORY_SCOPE_AGENT);
            __hip_atomic_store(&part[(size_t)O * YB + (size_t)o * YB + blockIdx.x],
                               S2, __ATOMIC_RELAXED, __HIP_MEMORY_SCOPE_AGENT);
        }
    }

    // ---- fence-free last-block finalize (replaces finalize_bn dispatch) ----
    // __syncthreads emits s_waitcnt vmcnt(0) (m97-verified) -> every wave's
    // part stores have COMPLETED at the coherent point before the ticket.
    __syncthreads();
    if (tid == 0) {
        unsigned prev = __hip_atomic_fetch_add(counter, 1u, __ATOMIC_RELAXED,
                                               __HIP_MEMORY_SCOPE_AGENT);
        sLast = (prev == gridDim.x * gridDim.y - 1u) ? 1 : 0;
    }
    __syncthreads();
    if (sLast) {
        // TPC threads per channel; fixed partition + fixed combine order.
        double* sd = (double*)sred;   // 8KB >= 256*2 doubles
        const int TPC = (O >= 256) ? 1 : (256 / O);
        const int chunk = YB / TPC;   // YB,chunk always multiples of 4 (or 8/1)
        const int o = (TPC == 1) ? tid : (tid / TPC);
        const int sub = (TPC == 1) ? 0 : (tid % TPC);
        // pass 1: per-thread partial over its chunk (4-way interleave, fixed)
        for (int ob = o; ob < O; ob += 256) {   // only loops when O > 256
            const double* ps = part + (size_t)ob * YB;
            const double* pq = part + (size_t)O * YB + (size_t)ob * YB;
            int y0 = sub * chunk, y1 = y0 + chunk;
            double s0 = 0.0, s1 = 0.0, s2a = 0.0, s3 = 0.0;
            double q0 = 0.0, q1 = 0.0, q2 = 0.0, q3 = 0.0;
            if (chunk >= 4) {
                for (int yb = y0; yb < y1; yb += 4) {
                    s0 += __hip_atomic_load(&ps[yb], __ATOMIC_RELAXED, __HIP_MEMORY_SCOPE_AGENT);
                    s1 += __hip_atomic_load(&ps[yb + 1], __ATOMIC_RELAXED, __HIP_MEMORY_SCOPE_AGENT);
                    s2a += __hip_atomic_load(&ps[yb + 2], __ATOMIC_RELAXED, __HIP_MEMORY_SCOPE_AGENT);
                    s3 += __hip_atomic_load(&ps[yb + 3], __ATOMIC_RELAXED, __HIP_MEMORY_SCOPE_AGENT);
                    q0 += __hip_atomic_load(&pq[yb], __ATOMIC_RELAXED, __HIP_MEMORY_SCOPE_AGENT);
                    q1 += __hip_atomic_load(&pq[yb + 1], __ATOMIC_RELAXED, __HIP_MEMORY_SCOPE_AGENT);
                    q2 += __hip_atomic_load(&pq[yb + 2], __ATOMIC_RELAXED, __HIP_MEMORY_SCOPE_AGENT);
                    q3 += __hip_atomic_load(&pq[yb + 3], __ATOMIC_RELAXED, __HIP_MEMORY_SCOPE_AGENT);
                }
            } else {
                for (int yb = y0; yb < y1; ++yb) {
                    s0 += __hip_atomic_load(&ps[yb], __ATOMIC_RELAXED, __HIP_MEMORY_SCOPE_AGENT);
                    q0 += __hip_atomic_load(&pq[yb], __ATOMIC_RELAXED, __HIP_MEMORY_SCOPE_AGENT);
                }
            }
            double S = (s0 + s1) + (s2a + s3);
            double S2 = (q0 + q1) + (q2 + q3);
            if (TPC == 1) {
                double mean = S * invM;
                double var = S2 * invM - mean * mean;
                float varf = (float)var;
                if (varf < 0.f) varf = 0.f;
                float sc = gvec[ob] * rsqrtf(varf + 1e-5f);
                scOut[ob] = sc;
                shOut[ob] = bvec[ob] - (float)mean * sc;
            }
        }
        if (TPC > 1) {
            // stage partials, fixed-order combine by sub==0 threads
            // (o < O always here since TPC>1 implies O <= 128 <= 256 threads)
            {
                const double* ps = part + (size_t)o * YB;   // recompute partial? no:
                (void)ps;
            }
            // recompute is wasteful; instead stage via LDS:
        }
        __syncthreads();
        if (TPC > 1) {
            // second pass: each thread re-derives its partial into LDS slot,
            // then sub==0 combines. To avoid recompute, do partial directly:
            const double* ps = part + (size_t)o * YB;
            const double* pq = part + (size_t)O * YB + (size_t)o * YB;
            int y0 = sub * chunk, y1 = y0 + chunk;
            double s0 = 0.0, s1 = 0.0, s2a = 0.0, s3 = 0.0;
            double q0 = 0.0, q1 = 0.0, q2 = 0.0, q3 = 0.0;
            for (int yb = y0; yb < y1; yb += 4) {
                s0 += __hip_atomic_load(&ps[yb], __ATOMIC_RELAXED, __HIP_MEMORY_SCOPE_AGENT);
                s1 += __hip_atomic_load(&ps[yb + 1], __ATOMIC_RELAXED, __HIP_MEMORY_SCOPE_AGENT);
                s2a += __hip_atomic_load(&ps[yb + 2], __ATOMIC_RELAXED, __HIP_MEMORY_SCOPE_AGENT);
                s3 += __hip_atomic_load(&ps[yb + 3], __ATOMIC_RELAXED, __HIP_MEMORY_SCOPE_AGENT);
                q0 += __hip_atomic_load(&pq[yb], __ATOMIC_RELAXED, __HIP_MEMORY_SCOPE_AGENT);
                q1 += __hip_atomic_load(&pq[yb + 1], __ATOMIC_RELAXED, __HIP_MEMORY_SCOPE_AGENT);
                q2 += __hip_atomic_load(&pq[yb + 2], __ATOMIC_RELAXED, __HIP_MEMORY_SCOPE_AGENT);
                q3 += __hip_atomic_load(&pq[yb + 3], __ATOMIC_RELAXED, __HIP_MEMORY_SCOPE_AGENT);
            }
            sd[tid * 2] = (s0 + s1) + (s2a + s3);
            sd[tid * 2 + 1] = (q0 + q1) + (q2 + q3);
            __syncthreads();
            if (sub == 0) {
                double S = 0.0, S2 = 0.0;
                for (int s = 0; s < TPC; ++s) {   // fixed ascending order
                    S += sd[(o * TPC + s) * 2];
                    S2 += sd[(o * TPC + s) * 2 + 1];
                }
                double mean = S * invM;
                double var = S2 * invM - mean * mean;
                float varf = (float)var;
                if (varf < 0.f) varf = 0.f;
                float sc = gvec[o] * rsqrtf(varf + 1e-5f);
                scOut[o] = sc;
                shOut[o] = bvec[o] - (float)mean * sc;
            }
        }
    }
}

// ---------------- BN + ReLU + max over K (+ optional SA2 query_ball) -------
__global__ __launch_bounds__(256) void bn_relu_max(
    const float* __restrict__ Y, const float* __restrict__ scale,
    const float* __restrict__ shift, float* __restrict__ out,
    int Stot, int K, int O, int nMain,
    const float* __restrict__ qbXyz, const float* __restrict__ qbCtr,
    int* __restrict__ qbOut)
{
    if ((int)blockIdx.x >= nMain) {   // piggyback: SA2 query_ball (4 waves)
        int wid = threadIdx.x >> 6, lane = threadIdx.x & 63;
        int gw = ((int)blockIdx.x - nMain) * 4 + wid;
        if (gw < 1024) qb2_dev(qbXyz, qbCtr, qbOut, gw, lane);
        return;
    }
    int idx = blockIdx.x * 256 + threadIdx.x;
    if (idx >= Stot * O) return;
    int s = idx / O;
    int o = idx - s * O;
    const float* basep = Y + (size_t)s * K * O + o;
    float sc = scale[o], sh = shift[o];
    float mx = 0.f;
    for (int k = 0; k < K; ++k) {
        float v = basep[(size_t)k * O] * sc + sh;
        v = fmaxf(v, 0.f);
        mx = fmaxf(mx, v);
    }
    out[idx] = mx;
}

// ============================================================================
extern "C" void kernel_launch(void* const* d_in, const int* in_sizes, int n_in,
                              void* d_out, int out_size, void* d_ws, size_t ws_size,
                              hipStream_t stream)
{
    const float* xin = (const float*)d_in[0];
    const float* w[9]; const float* g[9]; const float* bb[9];
    for (int i = 0; i < 9; ++i) {
        w[i]  = (const float*)d_in[1 + 3 * i];
        g[i]  = (const float*)d_in[2 + 3 * i];
        bb[i] = (const float*)d_in[3 + 3 * i];
    }

    char* base = (char*)d_ws;
    size_t off = 0;
    auto alloc = [&](size_t bytes) -> void* {
        void* p = base + off;
        off = (off + bytes + 255) & ~(size_t)255;
        return p;
    };
    const int OC[9][3] = {{64,4,8},{64,64,64},{128,64,64},
                          {128,131,136},{128,128,128},{256,128,128},
                          {256,259,264},{512,256,256},{1024,512,512}};
    size_t woff[10]; woff[0] = 0;
    for (int i = 0; i < 9; ++i) woff[i + 1] = woff[i] + (size_t)OC[i][0] * OC[i][2];

    // --- small / metadata region (memset-protected) ---
    int*    fps1   = (int*)alloc((size_t)4096 * 4);
    int*    fps2   = (int*)alloc((size_t)1024 * 4);
    int*    qb2    = (int*)alloc((size_t)65536 * 4);
    float*  nx1    = (float*)alloc((size_t)12288 * 4);
    float*  nx2    = (float*)alloc((size_t)3072 * 4);
    float*  feat1  = (float*)alloc((size_t)524288 * 4);
    float*  feat2  = (float*)alloc((size_t)262144 * 4);
    double* part   = (double*)alloc((size_t)262144 * 8);
    float*  scales = (float*)alloc((size_t)9 * 1024 * 4);
    float*  shifts = (float*)alloc((size_t)9 * 1024 * 4);
    unsigned* ctrs = (unsigned*)alloc((size_t)16 * 4);   // per-layer tickets
    unsigned short* WH = (unsigned short*)alloc(woff[9] * 2);
    unsigned short* WL = (unsigned short*)alloc(woff[9] * 2);
    const size_t zeroBytes = off;
    // --- big ping/pong buffers (fully written before read at every use) ---
    float*  XG = (float*)alloc((size_t)65536 * 136 * 4);
    float*  A  = (float*)alloc((size_t)16777216 * 4);
    if (off > ws_size) return;

    // Defensive zero of the metadata region only (~5 MB): indices, stats,
    // and the atomic tickets start at 0 every invocation.
    hipMemsetAsync(d_ws, 0, zeroBytes, stream);

    PWArgs pwa;
    for (int i = 0; i < 9; ++i) {
        pwa.w[i] = w[i]; pwa.off[i] = (unsigned)woff[i];
        pwa.O[i] = OC[i][0]; pwa.C[i] = OC[i][1]; pwa.CP[i] = OC[i][2];
    }
    const int nPrep = (int)((woff[9] + 255) / 256);

    auto gemm = [&](const float* X, const float* sc, const float* sh, int act,
                    int wi, float* Y, int YB, int OB, int AC, int CPW, int O,
                    int li, double invM) {
        gemm_fused<<<dim3(YB, OB), 256, 0, stream>>>(
            X, sc, sh, act, WH + woff[wi], WL + woff[wi], Y, part,
            AC, CPW, O, g[wi], bb[wi], scales + li * 1024, shifts + li * 1024,
            invM, ctrs + li);
    };

    // ---------------- SA1 ----------------
    fps_block<256, 16, 4><<<8 + nPrep, 256, 0, stream>>>(
        xin, 512, fps1, nx1, 8, pwa, WH, WL, (int)woff[9]);
    // qb_group1 blocks 0-1023: group; 1024-1031: SA2 single-wave FPS.
    qb_group1<<<1024 + 8, 256, 0, stream>>>(xin, nx1, XG, 1024, nx1, fps2, nx2);

    gemm(XG, nullptr, nullptr, 0, 0, A, 1024, 1, 8, 8, 64, 0, 1.0 / 131072.0);
    gemm(A, scales + 0, shifts + 0, 1, 1, XG, 1024, 1, 64, 64, 64, 1, 1.0 / 131072.0);
    gemm(XG, scales + 1024, shifts + 1024, 1, 2, A, 1024, 1, 64, 64, 128, 2, 1.0 / 131072.0);
    // bn_relu_max (2048 blocks) + SA2 query_ball (256 blocks) fused.
    bn_relu_max<<<2048 + 256, 256, 0, stream>>>(
        A, scales + 2048, shifts + 2048, feat1, 4096, 32, 128, 2048,
        nx1, nx2, qb2);

    // ---------------- SA2 ----------------
    group2_kernel<<<(65536 * 136) / 256, 256, 0, stream>>>(nx1, feat1, qb2, nx2, XG);
    gemm(XG, nullptr, nullptr, 0, 3, A, 512, 1, 136, 136, 128, 3, 1.0 / 65536.0);
    gemm(A, scales + 3072, shifts + 3072, 1, 4, XG, 512, 1, 128, 128, 128, 4, 1.0 / 65536.0);
    gemm(XG, scales + 4096, shifts + 4096, 1, 5, A, 512, 2, 128, 128, 256, 5, 1.0 / 65536.0);
    bn_relu_max<<<(1024 * 256) / 256, 256, 0, stream>>>(
        A, scales + 5120, shifts + 5120, feat2, 1024, 64, 256, 1024 * 256 / 256,
        nullptr, nullptr, nullptr);

    // ---------------- SA3 (group_all) ----------------
    group3_kernel<<<(1024 * 264 + 255) / 256, 256, 0, stream>>>(nx2, feat2, XG);
    gemm(XG, nullptr, nullptr, 0, 6, A, 8, 2, 264, 264, 256, 6, 1.0 / 1024.0);
    gemm(A, scales + 6144, shifts + 6144, 1, 7, XG, 8, 4, 256, 256, 512, 7, 1.0 / 1024.0);
    gemm(XG, scales + 7168, shifts + 7168, 1, 8, A, 8, 8, 512, 512, 1024, 8, 1.0 / 1024.0);
    bn_relu_max<<<(8 * 1024) / 256, 256, 0, stream>>>(
        A, scales + 8192, shifts + 8192, (float*)d_out, 8, 128, 1024,
        (8 * 1024) / 256, nullptr, nullptr, nullptr);
}

// Round 9
// 817.427 us; speedup vs baseline: 2.2229x; 2.1349x over previous
//
#include <hip/hip_runtime.h>

// ============================================================================
// TemporalPointNet (PointNet++ style) forward on MI355X.
// B=2, T=4 -> BT=8 "batches", N=4096 points, 4 coords (xyz + t).
// SA1: npoint=512, r=0.2, K=32, C_in=4,  MLP 64,64,128
// SA2: npoint=128, r=0.4, K=64, C_in=131, MLP 128,128,256
// SA3: group_all,          K=128, C_in=259, MLP 256,512,1024
//
// R20: finalize removal via f64 atomicAdd stats + consumer-side scale/shift.
//  R18 (per-block threadfence) and R19 (agent-scope atomic tail) both wrecked
//  the gemm: R19's VGPR_Count=72 proves the complex tail made the compiler
//  SPILL the 64-VGPR accumulator to scratch (296us/gemm, 74MB scratch writes).
//  R20 keeps the R13 gemm body VERBATIM and makes the handoff trivial:
//   - tail: per-channel block sums -> 2x atomicAdd(double) into partS/partQ
//     (O entries/layer, own slice per layer, memset-zeroed). Replaces the
//     part[o*YB+bx] stores. Double-add reordering ~1e-16 rel (thr 0.123).
//   - consumers derive scale/shift themselves: gemm head fills sScale/sShift
//     (LDS, <=512ch, exact finalize_bn formula); bn_relu_max computes its
//     channel inline. Identical inputs -> identical values in every block.
//     Visibility via kernel-boundary stream order (same as R13's part
//     handoff). NO fences, NO tickets, NO last-block tail.
//   - all 9 finalize_bn dispatches deleted. Dispatches 27 -> 17.
//  Keeps: prep_w piggyback (fps_block), fps_wave piggyback (qb_group1),
//  bn_relu_max+SA2-query_ball fusion. FPS chains byte-identical to R11/R13
//  measured-best (286us). GEMM MFMA math bit-identical to R13.
// ============================================================================

typedef short s16x8 __attribute__((ext_vector_type(8)));
typedef float f32x4 __attribute__((ext_vector_type(4)));

__device__ __forceinline__ unsigned short f2bf_rne(float f) {
    unsigned u = __float_as_uint(f);
    u += 0x7FFFu + ((u >> 16) & 1u);
    return (unsigned short)(u >> 16);
}
// split f32 -> (hi, lo) bf16 pair: hi = rne(v), lo = rne(v - hi)
__device__ __forceinline__ void f2bf_split(float v, unsigned short& hi,
                                           unsigned short& lo) {
    unsigned u = __float_as_uint(v);
    unsigned r = u + 0x7FFFu + ((u >> 16) & 1u);
    hi = (unsigned short)(r >> 16);
    float vh = __uint_as_float(r & 0xFFFF0000u);
    lo = f2bf_rne(v - vh);
}

__device__ __forceinline__ unsigned long long umax64(unsigned long long a,
                                                     unsigned long long b) {
    return a > b ? a : b;
}

// Wave64 max-reduce via DPP: 1 DPP + 1 max per step (R9 measured-best;
// R10/R12 variants regressed — do not touch).
__device__ __forceinline__ unsigned wred_umax63(unsigned v) {
    unsigned t;
    t = (unsigned)__builtin_amdgcn_update_dpp(0, (int)v, 0x111, 0xf, 0xf, true); if (t > v) v = t;
    t = (unsigned)__builtin_amdgcn_update_dpp(0, (int)v, 0x112, 0xf, 0xf, true); if (t > v) v = t;
    t = (unsigned)__builtin_amdgcn_update_dpp(0, (int)v, 0x114, 0xf, 0xf, true); if (t > v) v = t;
    t = (unsigned)__builtin_amdgcn_update_dpp(0, (int)v, 0x118, 0xf, 0xf, true); if (t > v) v = t;
    t = (unsigned)__builtin_amdgcn_update_dpp(0, (int)v, 0x142, 0xa, 0xf, true); if (t > v) v = t;
    t = (unsigned)__builtin_amdgcn_update_dpp(0, (int)v, 0x143, 0xc, 0xf, true); if (t > v) v = t;
    return v;
}

// Wave argmax of (dist, min-index). Exact first-occurrence argmax.
__device__ __forceinline__ void wave_argmax(unsigned dbits, unsigned nInv,
                                            unsigned& vmax, unsigned& iInv) {
    unsigned m = wred_umax63(dbits);
    vmax = (unsigned)__builtin_amdgcn_readlane((int)m, 63);
    unsigned cand = (dbits == vmax) ? nInv : 0u;
    unsigned im = wred_umax63(cand);
    iInv = (unsigned)__builtin_amdgcn_readlane((int)im, 63);
}

// ---------------- all-layer weight pre-split (device body) ----------------
struct PWArgs {
    const float* w[9];
    unsigned off[9];
    int O[9], C[9], CP[9];
};
__device__ __forceinline__ void prep_w_dev(const PWArgs& a,
                                           unsigned short* __restrict__ wh,
                                           unsigned short* __restrict__ wl,
                                           int i) {
    int l = 0;
#pragma unroll
    for (int k = 1; k < 9; ++k) if (i >= (int)a.off[k]) l = k;
    int li = i - (int)a.off[l];
    int CP = a.CP[l];
    int o = li / CP;
    int c = li - o * CP;
    float v = (c < a.C[l]) ? a.w[l][(size_t)o * a.C[l] + c] : 0.f;
    unsigned short h, lo;
    f2bf_split(v, h, lo);
    wh[i] = h; wl[i] = lo;
}

// ---------------- FPS (multi-wave): one block (NT thr) per batch ------------
// R7/R9 structure (measured best 286us). Blocks >= nFps run the weight
// pre-split (fully hidden in the FPS shadow).
template<int NT, int ITEMS, int STRIDE>
__global__ __launch_bounds__(NT) void fps_block(
    const float* __restrict__ pts, int npoint,
    int* __restrict__ outIdx, float* __restrict__ outXyz,
    int nFps, PWArgs pw, unsigned short* __restrict__ wh,
    unsigned short* __restrict__ wl, int wtotal)
{
    constexpr int N = NT * ITEMS;
    constexpr int NW = NT / 64;
    __shared__ float4 scoord[N];
    __shared__ unsigned long long wkey[2][NW];

    if (blockIdx.x >= nFps) {   // piggyback: weight split on idle CUs
        int i = (blockIdx.x - nFps) * NT + threadIdx.x;
        if (i < wtotal) prep_w_dev(pw, wh, wl, i);
        return;
    }

    const int b = blockIdx.x;
    const int tid = threadIdx.x;
    const int wid = tid >> 6;
    const int lane = tid & 63;
    const float* P = pts + (size_t)b * N * STRIDE;

    float px[ITEMS], py[ITEMS], pz[ITEMS], dloc[ITEMS];
#pragma unroll
    for (int w = 0; w < ITEMS; ++w) {
        int n = tid + w * NT;
        float x, y, z;
        if (STRIDE == 4) {
            float4 v = *(const float4*)(P + (size_t)n * 4);
            x = v.x; y = v.y; z = v.z;
        } else {
            x = P[(size_t)n * STRIDE + 0];
            y = P[(size_t)n * STRIDE + 1];
            z = P[(size_t)n * STRIDE + 2];
        }
        px[w] = x; py[w] = y; pz[w] = z;
        scoord[n] = make_float4(x, y, z, 0.f);
        dloc[w] = 1e10f;
    }
    __syncthreads();
    float4 c0 = scoord[0];
    float cx = c0.x, cy = c0.y, cz = c0.z;
    int far = 0;

    for (int i = 0; i < npoint; ++i) {
        if (tid == 0) {
            outIdx[(size_t)b * npoint + i] = far;
            outXyz[((size_t)b * npoint + i) * 3 + 0] = cx;
            outXyz[((size_t)b * npoint + i) * 3 + 1] = cy;
            outXyz[((size_t)b * npoint + i) * 3 + 2] = cz;
        }
        float bestV = -1.0f;
        int bestW = 0;
#pragma unroll
        for (int w = 0; w < ITEMS; ++w) {
            float dx = __fsub_rn(px[w], cx);
            float dy = __fsub_rn(py[w], cy);
            float dz = __fsub_rn(pz[w], cz);
            float d = __fadd_rn(__fadd_rn(__fmul_rn(dx, dx), __fmul_rn(dy, dy)),
                                __fmul_rn(dz, dz));
            float dd = fminf(dloc[w], d);
            dloc[w] = dd;
            if (dd > bestV) { bestV = dd; bestW = w; }  // strict > : lowest w kept
        }
        int bestN = tid + bestW * NT;   // n grows with w -> min n on tie
        unsigned vmax, iInv;
        wave_argmax(__float_as_uint(bestV), 0xFFFFFFFFu ^ (unsigned)bestN,
                    vmax, iInv);
        const int par = i & 1;
        if (lane == 0)
            wkey[par][wid] = ((unsigned long long)vmax << 32) | iInv;
        __syncthreads();   // single barrier per iteration (parity dbuf)
        unsigned long long kb = wkey[par][0];
#pragma unroll
        for (int w2 = 1; w2 < NW; ++w2) kb = umax64(kb, wkey[par][w2]);
        far = (int)(0xFFFFFFFFu ^ (unsigned)kb);
        float4 cc = scoord[far];   // broadcast, conflict-free
        cx = cc.x; cy = cc.y; cz = cc.z;
    }
}

// ---------------- FPS (single wave, device body, no barriers) ---------------
__device__ void fps_wave_dev(const float* __restrict__ pts, int npoint,
                             int* __restrict__ outIdx, float* __restrict__ outXyz,
                             int b, float4* scoord)
{
    constexpr int ITEMS = 8;
    constexpr int STRIDE = 3;
    constexpr int N = 64 * ITEMS;
    const int tid = threadIdx.x;   // 0..63
    const float* P = pts + (size_t)b * N * STRIDE;

    float px[ITEMS], py[ITEMS], pz[ITEMS], dloc[ITEMS];
#pragma unroll
    for (int w = 0; w < ITEMS; ++w) {
        int n = tid + w * 64;
        float x = P[(size_t)n * STRIDE + 0];
        float y = P[(size_t)n * STRIDE + 1];
        float z = P[(size_t)n * STRIDE + 2];
        px[w] = x; py[w] = y; pz[w] = z;
        scoord[n] = make_float4(x, y, z, 0.f);
        dloc[w] = 1e10f;
    }
    __threadfence_block();
    float4 c0 = scoord[0];
    float cx = c0.x, cy = c0.y, cz = c0.z;
    int far = 0;

    for (int i = 0; i < npoint; ++i) {
        if (tid == 0) {
            outIdx[(size_t)b * npoint + i] = far;
            outXyz[((size_t)b * npoint + i) * 3 + 0] = cx;
            outXyz[((size_t)b * npoint + i) * 3 + 1] = cy;
            outXyz[((size_t)b * npoint + i) * 3 + 2] = cz;
        }
        float bestV = -1.0f;
        int bestW = 0;
#pragma unroll
        for (int w = 0; w < ITEMS; ++w) {
            float dx = __fsub_rn(px[w], cx);
            float dy = __fsub_rn(py[w], cy);
            float dz = __fsub_rn(pz[w], cz);
            float d = __fadd_rn(__fadd_rn(__fmul_rn(dx, dx), __fmul_rn(dy, dy)),
                                __fmul_rn(dz, dz));
            float dd = fminf(dloc[w], d);
            dloc[w] = dd;
            if (dd > bestV) { bestV = dd; bestW = w; }
        }
        int bestN = tid + bestW * 64;
        unsigned vmax, iInv;
        wave_argmax(__float_as_uint(bestV), 0xFFFFFFFFu ^ (unsigned)bestN,
                    vmax, iInv);
        far = (int)(0xFFFFFFFFu ^ iInv);
        float4 cc = scoord[far];
        cx = cc.x; cy = cc.y; cz = cc.z;
    }
}

// ---------------- fused query_ball + group for SA1 (+fps_wave piggyback) ----
__global__ __launch_bounds__(256) void qb_group1(
    const float* __restrict__ xyz /*(8,4096,4)*/,
    const float* __restrict__ ctr /*(8*512,3)*/,
    float* __restrict__ out /*(8*512*32, 8)*/,
    int nQb, const float* __restrict__ fpsPts,
    int* __restrict__ fpsIdx, float* __restrict__ fpsXyz)
{
    __shared__ float4 scoord[512];
    if ((int)blockIdx.x >= nQb) {   // piggyback: single-wave FPS (SA2)
        if (threadIdx.x < 64)
            fps_wave_dev(fpsPts, 128, fpsIdx, fpsXyz,
                         (int)blockIdx.x - nQb, scoord);
        return;
    }
    int gw = (blockIdx.x * 256 + threadIdx.x) >> 6;
    int lane = threadIdx.x & 63;
    if (gw >= 4096) return;
    int b = gw >> 9;
    const float* P = xyz + (size_t)b * 4096 * 4;
    float cx = ctr[(size_t)gw * 3 + 0];
    float cy = ctr[(size_t)gw * 3 + 1];
    float cz = ctr[(size_t)gw * 3 + 2];
    float* out0 = out + (size_t)gw * 32 * 8;
    int cnt = 0;
    float f0x = 0.f, f0y = 0.f, f0z = 0.f, f0t = 0.f;
    bool haveFirst = false;
    for (int base = 0; base < 4096 && cnt < 32; base += 64) {
        int n = base + lane;
        float4 p = *(const float4*)(P + (size_t)n * 4);
        float ex = __fsub_rn(p.x, cx);
        float ey = __fsub_rn(p.y, cy);
        float ez = __fsub_rn(p.z, cz);
        float d = __fadd_rn(__fadd_rn(__fmul_rn(ex, ex), __fmul_rn(ey, ey)),
                            __fmul_rn(ez, ez));
        bool inb = !(d > 0.04f);
        unsigned long long mask = __ballot(inb);
        if (mask) {
            if (!haveFirst) {
                int fl = (int)__builtin_ctzll(mask);   // wave-uniform
                f0x = __shfl(ex, fl); f0y = __shfl(ey, fl);
                f0z = __shfl(ez, fl); f0t = __shfl(p.w, fl);
                haveFirst = true;
            }
            if (inb) {
                int pos = cnt + __builtin_popcountll(mask & ((1ull << lane) - 1ull));
                if (pos < 32) {
                    float* o = out0 + (size_t)pos * 8;
                    *(float4*)o = make_float4(ex, ey, ez, p.w);
                    *(float4*)(o + 4) = make_float4(0.f, 0.f, 0.f, 0.f);
                }
            }
            cnt += (int)__builtin_popcountll(mask);
        }
    }
    if (cnt > 32) cnt = 32;
    for (int p2 = cnt + lane; p2 < 32; p2 += 64) {
        float* o = out0 + (size_t)p2 * 8;
        *(float4*)o = make_float4(f0x, f0y, f0z, f0t);
        *(float4*)(o + 4) = make_float4(0.f, 0.f, 0.f, 0.f);
    }
}

// ---------------- query_ball body (SA2 geometry, device) ----------------
__device__ __forceinline__ void qb2_dev(
    const float* __restrict__ xyz, const float* __restrict__ centers,
    int* __restrict__ outIdx, int gw, int lane)
{
    const int N = 512, stride = 3, S = 128, nsample = 64;
    const float r2 = 0.16f;
    int b = gw / S;
    const float* P = xyz + (size_t)b * N * stride;
    float cx = centers[(size_t)gw * 3 + 0];
    float cy = centers[(size_t)gw * 3 + 1];
    float cz = centers[(size_t)gw * 3 + 2];
    int* out = outIdx + (size_t)gw * nsample;
    int cnt = 0;
    int firstIdx = 0;
    bool haveFirst = false;
    for (int base = 0; base < N && cnt < nsample; base += 64) {
        int n = base + lane;
        bool inb = false;
        if (n < N) {
            float dx = __fsub_rn(cx, P[(size_t)n * stride + 0]);
            float dy = __fsub_rn(cy, P[(size_t)n * stride + 1]);
            float dz = __fsub_rn(cz, P[(size_t)n * stride + 2]);
            float d = __fadd_rn(__fadd_rn(__fmul_rn(dx, dx), __fmul_rn(dy, dy)),
                                __fmul_rn(dz, dz));
            inb = !(d > r2);
        }
        unsigned long long mask = __ballot(inb);
        if (mask) {
            if (!haveFirst) { firstIdx = base + __builtin_ctzll(mask); haveFirst = true; }
            if (inb) {
                int pos = cnt + __builtin_popcountll(mask & ((1ull << lane) - 1ull));
                if (pos < nsample) out[pos] = n;
            }
            cnt += (int)__builtin_popcountll(mask);
        }
    }
    if (cnt > nsample) cnt = nsample;
    for (int p = cnt + lane; p < nsample; p += 64) out[p] = firstIdx;
}

// ---------------- grouping kernels (f32, padded rows) ----------------------
__global__ __launch_bounds__(256) void group2_kernel(
    const float* __restrict__ xyz, const float* __restrict__ feat,
    const int* __restrict__ qb, const float* __restrict__ ctr,
    float* __restrict__ out)
{
    int i = blockIdx.x * 256 + threadIdx.x;
    if (i >= 65536 * 136) return;
    int sk = i / 136;
    int c = i - sk * 136;
    int b = sk / (128 * 64);
    int bs = sk / 64;
    int idx = qb[sk];
    idx = (idx < 0) ? 0 : (idx > 511 ? 511 : idx);
    float v = 0.f;
    if (c < 3)        v = __fsub_rn(xyz[((size_t)b * 512 + idx) * 3 + c], ctr[(size_t)bs * 3 + c]);
    else if (c < 131) v = feat[((size_t)b * 512 + idx) * 128 + (c - 3)];
    out[i] = v;
}

__global__ __launch_bounds__(256) void group3_kernel(
    const float* __restrict__ ctr2, const float* __restrict__ feat2,
    float* __restrict__ out)
{
    int i = blockIdx.x * 256 + threadIdx.x;
    if (i >= 1024 * 264) return;
    int sk = i / 264;
    int c = i - sk * 264;
    float v = 0.f;
    if (c < 3)        v = ctr2[(size_t)sk * 3 + c];
    else if (c < 259) v = feat2[(size_t)sk * 256 + (c - 3)];
    out[i] = v;
}

// ---------------- fused GEMM: Y = act(X) * W^T + BN stat-sums --------------
// R13 body VERBATIM except:
//  - head: if applyAct, derive sScale/sShift in LDS from PREVIOUS layer's
//    summed stats (pSin/pQin, O<=512 channels; exact finalize_bn formula).
//  - tail: per-channel block sums go out via 2x atomicAdd(double) into this
//    layer's partS/partQ (replaces part[o*YB+bx] stores). No fences/tickets.
__global__ __launch_bounds__(256) void gemm_fused(
    const float* __restrict__ X,
    const double* __restrict__ pSin, const double* __restrict__ pQin,
    const float* __restrict__ gIn, const float* __restrict__ bIn,
    double invMin, int applyAct,
    const unsigned short* __restrict__ Bh, const unsigned short* __restrict__ Bl,
    float* __restrict__ Y,
    double* __restrict__ pSout, double* __restrict__ pQout,
    int AC, int CPW, int O)
{
    constexpr int PITCH = 40;
    __shared__ __align__(16) unsigned short sAh[128 * PITCH];
    __shared__ __align__(16) unsigned short sAl[128 * PITCH];
    __shared__ __align__(16) unsigned short sBh[128 * PITCH];
    __shared__ __align__(16) unsigned short sBl[128 * PITCH];
    __shared__ float sred[2048];
    __shared__ float sScale[512];
    __shared__ float sShift[512];

    const int tid = threadIdx.x;
    const int lane = tid & 63;
    const int wid = tid >> 6;
    const int col15 = lane & 15;
    const int quad = lane >> 4;
    const int wm = (wid >> 1) * 64;
    const int wo = (wid & 1) * 64;
    const int m0 = blockIdx.x * 128;
    const int o0 = blockIdx.y * 128;
    const int lr = tid >> 2;
    const int lc = (tid & 3) * 8;

    // head: derive this layer's input BN scale/shift from summed stats.
    if (applyAct) {
        for (int c = tid; c < AC; c += 256) {
            double S = pSin[c], Q = pQin[c];
            double mean = S * invMin;
            double var = Q * invMin - mean * mean;
            float varf = (float)var;
            if (varf < 0.f) varf = 0.f;
            float sc = gIn[c] * rsqrtf(varf + 1e-5f);
            sScale[c] = sc;
            sShift[c] = bIn[c] - (float)mean * sc;
        }
    }
    __syncthreads();

    f32x4 acc[4][4];
#pragma unroll
    for (int mt = 0; mt < 4; ++mt)
#pragma unroll
        for (int ot = 0; ot < 4; ++ot)
            acc[mt][ot] = {0.f, 0.f, 0.f, 0.f};

    for (int k0 = 0; k0 < CPW; k0 += 32) {
#pragma unroll
        for (int it = 0; it < 2; ++it) {
            int r = lr + it * 64;
            int c = k0 + lc;
            unsigned short h[8], l[8];
            if (c + 8 <= AC) {
                const float* xr = X + (size_t)(m0 + r) * AC + c;
                float4 v0 = *(const float4*)xr;
                float4 v1 = *(const float4*)(xr + 4);
                float vv[8] = {v0.x, v0.y, v0.z, v0.w, v1.x, v1.y, v1.z, v1.w};
#pragma unroll
                for (int j = 0; j < 8; ++j) {
                    float v = vv[j];
                    if (applyAct) v = fmaxf(v * sScale[c + j] + sShift[c + j], 0.f);
                    f2bf_split(v, h[j], l[j]);
                }
            } else {
#pragma unroll
                for (int j = 0; j < 8; ++j) { h[j] = 0; l[j] = 0; }
            }
            *(ushort4*)&sAh[r * PITCH + lc] = make_ushort4(h[0], h[1], h[2], h[3]);
            *(ushort4*)&sAh[r * PITCH + lc + 4] = make_ushort4(h[4], h[5], h[6], h[7]);
            *(ushort4*)&sAl[r * PITCH + lc] = make_ushort4(l[0], l[1], l[2], l[3]);
            *(ushort4*)&sAl[r * PITCH + lc + 4] = make_ushort4(l[4], l[5], l[6], l[7]);
        }
#pragma unroll
        for (int it = 0; it < 2; ++it) {
            int r = lr + it * 64;
            int c = k0 + lc;
            int o = o0 + r;
            uint4 vh = {0, 0, 0, 0}, vl = {0, 0, 0, 0};
            if (o < O && c < CPW) {
                size_t goff = (size_t)o * CPW + c;
                vh = *(const uint4*)(Bh + goff);
                vl = *(const uint4*)(Bl + goff);
            }
            *(uint4*)&sBh[r * PITCH + lc] = vh;
            *(uint4*)&sBl[r * PITCH + lc] = vl;
        }
        __syncthreads();
        s16x8 ah[4], al[4], bh[4], bl[4];
#pragma unroll
        for (int mt = 0; mt < 4; ++mt) {
            int rowoff = (wm + mt * 16 + col15) * PITCH + quad * 8;
            ah[mt] = *(const s16x8*)&sAh[rowoff];
            al[mt] = *(const s16x8*)&sAl[rowoff];
        }
#pragma unroll
        for (int ot = 0; ot < 4; ++ot) {
            int rowoff = (wo + ot * 16 + col15) * PITCH + quad * 8;
            bh[ot] = *(const s16x8*)&sBh[rowoff];
            bl[ot] = *(const s16x8*)&sBl[rowoff];
        }
#pragma unroll
        for (int mt = 0; mt < 4; ++mt)
#pragma unroll
            for (int ot = 0; ot < 4; ++ot) {
                acc[mt][ot] = __builtin_amdgcn_mfma_f32_16x16x32_bf16(
                    ah[mt], bl[ot], acc[mt][ot], 0, 0, 0);
                acc[mt][ot] = __builtin_amdgcn_mfma_f32_16x16x32_bf16(
                    al[mt], bh[ot], acc[mt][ot], 0, 0, 0);
                acc[mt][ot] = __builtin_amdgcn_mfma_f32_16x16x32_bf16(
                    ah[mt], bh[ot], acc[mt][ot], 0, 0, 0);
            }
        __syncthreads();
    }
#pragma unroll
    for (int mt = 0; mt < 4; ++mt)
#pragma unroll
        for (int ot = 0; ot < 4; ++ot) {
            int og = o0 + wo + ot * 16 + col15;
            if (og < O) {
#pragma unroll
                for (int r = 0; r < 4; ++r) {
                    int mg = m0 + wm + mt * 16 + quad * 4 + r;
                    Y[(size_t)mg * O + og] = acc[mt][ot][r];
                }
            }
        }
    // BN stats epilogue (R13-identical fixed-order block combine), then two
    // f64 atomicAdds per channel (simple tail — no register-pressure bomb).
#pragma unroll
    for (int ot = 0; ot < 4; ++ot) {
        float s = 0.f, s2 = 0.f;
#pragma unroll
        for (int mt = 0; mt < 4; ++mt)
#pragma unroll
            for (int r = 0; r < 4; ++r) {
                float v = acc[mt][ot][r];
                s += v;
                s2 += v * v;
            }
        int slot = ((wid * 4 + quad) * 16 + col15) * 4 + ot;
        sred[slot * 2] = s;
        sred[slot * 2 + 1] = s2;
    }
    __syncthreads();
    if (tid < 128) {
        int col = tid;
        int o = o0 + col;
        if (o < O) {
            int cb = col >> 6;
            int ot = (col & 63) >> 4;
            int c15 = col & 15;
            double S = 0.0, S2 = 0.0;
#pragma unroll
            for (int wp = 0; wp < 2; ++wp) {
                int wd = cb + wp * 2;
#pragma unroll
                for (int q = 0; q < 4; ++q) {
                    int slot = ((wd * 4 + q) * 16 + c15) * 4 + ot;
                    S += (double)sred[slot * 2];
                    S2 += (double)sred[slot * 2 + 1];
                }
            }
            atomicAdd(&pSout[o], S);
            atomicAdd(&pQout[o], S2);
        }
    }
}

// ---------------- BN + ReLU + max over K (+ optional SA2 query_ball) -------
// Computes its channel's scale/shift inline from the summed stats (identical
// formula/inputs in every block -> identical values; no finalize dispatch).
__global__ __launch_bounds__(256) void bn_relu_max(
    const float* __restrict__ Y,
    const double* __restrict__ pS, const double* __restrict__ pQ,
    const float* __restrict__ gv, const float* __restrict__ bv, double invM,
    float* __restrict__ out, int Stot, int K, int O, int nMain,
    const float* __restrict__ qbXyz, const float* __restrict__ qbCtr,
    int* __restrict__ qbOut)
{
    if ((int)blockIdx.x >= nMain) {   // piggyback: SA2 query_ball (4 waves)
        int wid = threadIdx.x >> 6, lane = threadIdx.x & 63;
        int gw = ((int)blockIdx.x - nMain) * 4 + wid;
        if (gw < 1024) qb2_dev(qbXyz, qbCtr, qbOut, gw, lane);
        return;
    }
    int idx = blockIdx.x * 256 + threadIdx.x;
    if (idx >= Stot * O) return;
    int s = idx / O;
    int o = idx - s * O;
    double S = pS[o], Q = pQ[o];
    double mean = S * invM;
    double var = Q * invM - mean * mean;
    float varf = (float)var;
    if (varf < 0.f) varf = 0.f;
    float sc = gv[o] * rsqrtf(varf + 1e-5f);
    float sh = bv[o] - (float)mean * sc;
    const float* basep = Y + (size_t)s * K * O + o;
    float mx = 0.f;
    for (int k = 0; k < K; ++k) {
        float v = basep[(size_t)k * O] * sc + sh;
        v = fmaxf(v, 0.f);
        mx = fmaxf(mx, v);
    }
    out[idx] = mx;
}

// ============================================================================
extern "C" void kernel_launch(void* const* d_in, const int* in_sizes, int n_in,
                              void* d_out, int out_size, void* d_ws, size_t ws_size,
                              hipStream_t stream)
{
    const float* xin = (const float*)d_in[0];
    const float* w[9]; const float* g[9]; const float* bb[9];
    for (int i = 0; i < 9; ++i) {
        w[i]  = (const float*)d_in[1 + 3 * i];
        g[i]  = (const float*)d_in[2 + 3 * i];
        bb[i] = (const float*)d_in[3 + 3 * i];
    }

    char* base = (char*)d_ws;
    size_t off = 0;
    auto alloc = [&](size_t bytes) -> void* {
        void* p = base + off;
        off = (off + bytes + 255) & ~(size_t)255;
        return p;
    };
    const int OC[9][3] = {{64,4,8},{64,64,64},{128,64,64},
                          {128,131,136},{128,128,128},{256,128,128},
                          {256,259,264},{512,256,256},{1024,512,512}};
    size_t woff[10]; woff[0] = 0;
    for (int i = 0; i < 9; ++i) woff[i + 1] = woff[i] + (size_t)OC[i][0] * OC[i][2];

    // --- small / metadata region (memset-protected) ---
    int*    fps1   = (int*)alloc((size_t)4096 * 4);
    int*    fps2   = (int*)alloc((size_t)1024 * 4);
    int*    qb2    = (int*)alloc((size_t)65536 * 4);
    float*  nx1    = (float*)alloc((size_t)12288 * 4);
    float*  nx2    = (float*)alloc((size_t)3072 * 4);
    float*  feat1  = (float*)alloc((size_t)524288 * 4);
    float*  feat2  = (float*)alloc((size_t)262144 * 4);
    double* partS  = (double*)alloc((size_t)9 * 1024 * 8);   // per-layer sums
    double* partQ  = (double*)alloc((size_t)9 * 1024 * 8);   // per-layer sumsq
    unsigned short* WH = (unsigned short*)alloc(woff[9] * 2);
    unsigned short* WL = (unsigned short*)alloc(woff[9] * 2);
    const size_t zeroBytes = off;
    // --- big ping/pong buffers (fully written before read at every use) ---
    float*  XG = (float*)alloc((size_t)65536 * 136 * 4);
    float*  A  = (float*)alloc((size_t)16777216 * 4);
    if (off > ws_size) return;

    // Defensive zero of the metadata region only (~5 MB): indices and the
    // per-layer stat accumulators start at 0 every invocation.
    hipMemsetAsync(d_ws, 0, zeroBytes, stream);

    PWArgs pwa;
    for (int i = 0; i < 9; ++i) {
        pwa.w[i] = w[i]; pwa.off[i] = (unsigned)woff[i];
        pwa.O[i] = OC[i][0]; pwa.C[i] = OC[i][1]; pwa.CP[i] = OC[i][2];
    }
    const int nPrep = (int)((woff[9] + 255) / 256);

    auto gemm = [&](const float* X, int prevLi, double invMprev, int li,
                    float* Y, int YB, int OB, int AC, int CPW, int O) {
        gemm_fused<<<dim3(YB, OB), 256, 0, stream>>>(
            X,
            prevLi >= 0 ? partS + (size_t)prevLi * 1024 : nullptr,
            prevLi >= 0 ? partQ + (size_t)prevLi * 1024 : nullptr,
            prevLi >= 0 ? g[prevLi] : nullptr,
            prevLi >= 0 ? bb[prevLi] : nullptr,
            invMprev, prevLi >= 0 ? 1 : 0,
            WH + woff[li], WL + woff[li], Y,
            partS + (size_t)li * 1024, partQ + (size_t)li * 1024,
            AC, CPW, O);
    };

    const double inv1 = 1.0 / 131072.0;
    const double inv2 = 1.0 / 65536.0;
    const double inv3 = 1.0 / 1024.0;

    // ---------------- SA1 ----------------
    fps_block<256, 16, 4><<<8 + nPrep, 256, 0, stream>>>(
        xin, 512, fps1, nx1, 8, pwa, WH, WL, (int)woff[9]);
    // qb_group1 blocks 0-1023: group; 1024-1031: SA2 single-wave FPS.
    qb_group1<<<1024 + 8, 256, 0, stream>>>(xin, nx1, XG, 1024, nx1, fps2, nx2);

    gemm(XG, -1, 0.0, 0, A, 1024, 1, 8, 8, 64);
    gemm(A, 0, inv1, 1, XG, 1024, 1, 64, 64, 64);
    gemm(XG, 1, inv1, 2, A, 1024, 1, 64, 64, 128);
    // bn_relu_max (2048 blocks) + SA2 query_ball (256 blocks) fused.
    bn_relu_max<<<2048 + 256, 256, 0, stream>>>(
        A, partS + 2 * 1024, partQ + 2 * 1024, g[2], bb[2], inv1,
        feat1, 4096, 32, 128, 2048, nx1, nx2, qb2);

    // ---------------- SA2 ----------------
    group2_kernel<<<(65536 * 136) / 256, 256, 0, stream>>>(nx1, feat1, qb2, nx2, XG);
    gemm(XG, -1, 0.0, 3, A, 512, 1, 136, 136, 128);
    gemm(A, 3, inv2, 4, XG, 512, 1, 128, 128, 128);
    gemm(XG, 4, inv2, 5, A, 512, 2, 128, 128, 256);
    bn_relu_max<<<(1024 * 256) / 256, 256, 0, stream>>>(
        A, partS + 5 * 1024, partQ + 5 * 1024, g[5], bb[5], inv2,
        feat2, 1024, 64, 256, 1024 * 256 / 256, nullptr, nullptr, nullptr);

    // ---------------- SA3 (group_all) ----------------
    group3_kernel<<<(1024 * 264 + 255) / 256, 256, 0, stream>>>(nx2, feat2, XG);
    gemm(XG, -1, 0.0, 6, A, 8, 2, 264, 264, 256);
    gemm(A, 6, inv3, 7, XG, 8, 4, 256, 256, 512);
    gemm(XG, 7, inv3, 8, A, 8, 8, 512, 512, 1024);
    bn_relu_max<<<(8 * 1024) / 256, 256, 0, stream>>>(
        A, partS + 8 * 1024, partQ + 8 * 1024, g[8], bb[8], inv3,
        (float*)d_out, 8, 128, 1024, (8 * 1024) / 256,
        nullptr, nullptr, nullptr);
}